// Round 1
// baseline (408.388 us; speedup 1.0000x reference)
//
#include <hip/hip_runtime.h>

typedef _Float16 f16;
typedef _Float16 f16x8 __attribute__((ext_vector_type(8)));
typedef _Float16 f16x4 __attribute__((ext_vector_type(4)));
typedef float f32x4 __attribute__((ext_vector_type(4)));

#define HID 2048
#define NH 32
#define NKV 8
#define HD 64
#define SEQ 2048
#define NB 2

__device__ __forceinline__ void gload_lds16(const void* g, void* l) {
  __builtin_amdgcn_global_load_lds((const __attribute__((address_space(1))) void*)g,
                                   (__attribute__((address_space(3))) void*)l, 16, 0, 0);
}

// ---------------- f32 -> f16 convert ----------------
__global__ __launch_bounds__(256) void cvt_f16(const float* __restrict__ in,
                                               f16* __restrict__ out, int n4) {
  int i = blockIdx.x * 256 + threadIdx.x;
  if (i < n4) {
    float4 v = ((const float4*)in)[i];
    f16x4 o = { (f16)v.x, (f16)v.y, (f16)v.z, (f16)v.w };
    ((f16x4*)out)[i] = o;
  }
}

// ---------------- GEMM: C[M,N] = A[M,K] * B[N,K]^T ----------------
// 128x128 tile, BK=64, 4 waves (2x2 of 64x64), 16x16x32 f16 MFMA.
// LDS double-buffered, global_load_lds w/ pre-swizzled source (slot ^= row&7).
template <typename CT>
__global__ __launch_bounds__(256) void gemm_bt(const f16* __restrict__ A,
                                               const f16* __restrict__ Bm,
                                               CT* __restrict__ C,
                                               int M, int N, int K) {
  __shared__ f16 As[2][128 * 64];
  __shared__ f16 Bs[2][128 * 64];
  const int t = threadIdx.x;
  const int lane = t & 63;
  const int w = t >> 6;
  const int wr = w >> 1, wc = w & 1;
  const int g = lane >> 4;
  const int lr = lane & 15;
  const int m0 = blockIdx.y * 128;
  const int n0 = blockIdx.x * 128;

  f32x4 acc[4][4] = {};

  const int nkt = K / 64;

  auto stage = [&](int buf, int kt) {
    const int k0 = kt * 64;
#pragma unroll
    for (int i = 0; i < 4; ++i) {
      int c = w * 4 + i;
      int o = c * 1024 + lane * 16;
      int row = o >> 7;
      int ss = ((o >> 4) & 7) ^ (row & 7);
      const char* srcA = (const char*)A + ((size_t)(m0 + row) * K + k0) * 2 + ss * 16;
      gload_lds16(srcA, (char*)(&As[buf][0]) + c * 1024);
      const char* srcB = (const char*)Bm + ((size_t)(n0 + row) * K + k0) * 2 + ss * 16;
      gload_lds16(srcB, (char*)(&Bs[buf][0]) + c * 1024);
    }
  };

  stage(0, 0);
  __syncthreads();
  int cur = 0;
  for (int kt = 0; kt < nkt; ++kt) {
    if (kt + 1 < nkt) stage(cur ^ 1, kt + 1);
#pragma unroll
    for (int ks = 0; ks < 2; ++ks) {
      f16x8 af[4], bf[4];
#pragma unroll
      for (int mf = 0; mf < 4; ++mf) {
        int row = wr * 64 + mf * 16 + lr;
        int slot = (g + 4 * ks) ^ (row & 7);
        af[mf] = *(const f16x8*)((const char*)(&As[cur][0]) + row * 128 + slot * 16);
      }
#pragma unroll
      for (int nf = 0; nf < 4; ++nf) {
        int row = wc * 64 + nf * 16 + lr;
        int slot = (g + 4 * ks) ^ (row & 7);
        bf[nf] = *(const f16x8*)((const char*)(&Bs[cur][0]) + row * 128 + slot * 16);
      }
#pragma unroll
      for (int mf = 0; mf < 4; ++mf)
#pragma unroll
        for (int nf = 0; nf < 4; ++nf)
          acc[mf][nf] = __builtin_amdgcn_mfma_f32_16x16x32_f16(af[mf], bf[nf], acc[mf][nf], 0, 0, 0);
    }
    __syncthreads();
    cur ^= 1;
  }

#pragma unroll
  for (int mf = 0; mf < 4; ++mf)
#pragma unroll
    for (int nf = 0; nf < 4; ++nf)
#pragma unroll
      for (int r = 0; r < 4; ++r) {
        int mm = m0 + wr * 64 + mf * 16 + g * 4 + r;
        int nn = n0 + wc * 64 + nf * 16 + lr;
        C[(size_t)mm * N + nn] = (CT)acc[mf][nf][r];
      }
}

// ---------------- RMSNorm over 64-elem head rows (in place) ----------------
__global__ __launch_bounds__(256) void rmsnorm64(f16* __restrict__ p,
                                                 const float* __restrict__ w,
                                                 int heads_per_row, int row_stride,
                                                 int total_chunks, float extra) {
  int c = blockIdx.x * 4 + (threadIdx.x >> 6);
  int lane = threadIdx.x & 63;
  if (c >= total_chunks) return;
  int m = c / heads_per_row, hh = c % heads_per_row;
  f16* base = p + (size_t)m * row_stride + hh * 64;
  float x = (float)base[lane];
  float ss = x * x;
#pragma unroll
  for (int d = 1; d < 64; d <<= 1) ss += __shfl_xor(ss, d);
  float sc = rsqrtf(ss * (1.0f / 64.0f) + 1e-6f) * extra;
  base[lane] = (f16)(x * sc * w[lane]);
}

// ---------------- V transpose: KV[:,512:] -> VT[b][hk][d][s] ----------------
__global__ __launch_bounds__(256) void vtrans(const f16* __restrict__ KV,
                                              f16* __restrict__ VT) {
  __shared__ f16 tile[64][72];
  int t = threadIdx.x;
  int st = blockIdx.x, hk = blockIdx.y, b = blockIdx.z;
#pragma unroll
  for (int p = 0; p < 2; ++p) {
    int idx = p * 256 + t;
    int s = idx >> 3, c8 = (idx & 7) * 8;
    f16x8 v = *(const f16x8*)(KV + (size_t)(b * SEQ + st * 64 + s) * 1024 + 512 + hk * 64 + c8);
    *(f16x8*)(&tile[s][c8]) = v;
  }
  __syncthreads();
#pragma unroll
  for (int p = 0; p < 2; ++p) {
    int idx = p * 256 + t;
    int d = idx >> 3, s8 = (idx & 7) * 8;
    f16x8 ov;
#pragma unroll
    for (int j = 0; j < 8; ++j) ov[j] = tile[s8 + j][d];
    *(f16x8*)(VT + ((size_t)((b * NKV + hk) * 64) + d) * SEQ + st * 64 + s8) = ov;
  }
}

// ---------------- causal GQA flash attention ----------------
// block = (qt, h, b); 4 waves x 16 q-rows; KV tile 64.
__global__ __launch_bounds__(256) void attn(const f16* __restrict__ Q,
                                            const f16* __restrict__ KV,
                                            const f16* __restrict__ VT,
                                            f16* __restrict__ AO) {
  __shared__ f16 Ks[64 * 64];   // [kv][d], slot-swizzled
  __shared__ f16 Vs[64 * 64];   // V^T: [d][kv], slot-swizzled
  __shared__ f16 Ps[4][16 * 64];
  const int t = threadIdx.x, lane = t & 63, w = t >> 6;
  const int g = lane >> 4, lr = lane & 15;
  const int qt = blockIdx.x, h = blockIdx.y, b = blockIdx.z;
  const int hk = h >> 2;
  const int q0 = qt * 64;

  const size_t qrow = (size_t)(b * SEQ + q0 + w * 16 + lr);
  f16x8 qf[2];
  qf[0] = *(const f16x8*)(Q + qrow * HID + h * 64 + g * 8);
  qf[1] = *(const f16x8*)(Q + qrow * HID + h * 64 + g * 8 + 32);

  f32x4 oacc[4] = {};
  float mrow[4], lrow[4];
#pragma unroll
  for (int r = 0; r < 4; ++r) { mrow[r] = -1e30f; lrow[r] = 0.0f; }

  char* Pw = (char*)(&Ps[w][0]);
  const int nkt = qt + 1;
  for (int kt = 0; kt < nkt; ++kt) {
    __syncthreads();
#pragma unroll
    for (int i = 0; i < 2; ++i) {
      int c = w * 2 + i;
      int o = c * 1024 + lane * 16;
      int row = o >> 7;
      int ss = ((o >> 4) & 7) ^ (row & 7);
      gload_lds16((const char*)KV + ((size_t)(b * SEQ + kt * 64 + row) * 1024 + hk * 64) * 2 + ss * 16,
                  (char*)Ks + c * 1024);
      gload_lds16((const char*)VT + (((size_t)((b * NKV + hk) * 64) + row) * SEQ + kt * 64) * 2 + ss * 16,
                  (char*)Vs + c * 1024);
    }
    __syncthreads();

    // S = Q K^T (pre-scaled by 1/8 folded into Q)
    f32x4 sacc[4] = {};
#pragma unroll
    for (int ks = 0; ks < 2; ++ks) {
      f16x8 kf[4];
#pragma unroll
      for (int nf = 0; nf < 4; ++nf) {
        int row = nf * 16 + lr;
        int slot = (g + 4 * ks) ^ (row & 7);
        kf[nf] = *(const f16x8*)((const char*)Ks + row * 128 + slot * 16);
      }
#pragma unroll
      for (int nf = 0; nf < 4; ++nf)
        sacc[nf] = __builtin_amdgcn_mfma_f32_16x16x32_f16(qf[ks], kf[nf], sacc[nf], 0, 0, 0);
    }

    if (kt == qt) {
#pragma unroll
      for (int nf = 0; nf < 4; ++nf) {
        int kv = kt * 64 + nf * 16 + lr;
#pragma unroll
        for (int r = 0; r < 4; ++r) {
          int qq = q0 + w * 16 + g * 4 + r;
          if (kv > qq) sacc[nf][r] = -1e30f;
        }
      }
    }

    float mt[4];
#pragma unroll
    for (int r = 0; r < 4; ++r)
      mt[r] = fmaxf(fmaxf(sacc[0][r], sacc[1][r]), fmaxf(sacc[2][r], sacc[3][r]));
#pragma unroll
    for (int d = 1; d < 16; d <<= 1)
#pragma unroll
      for (int r = 0; r < 4; ++r) mt[r] = fmaxf(mt[r], __shfl_xor(mt[r], d));

    float corr[4];
#pragma unroll
    for (int r = 0; r < 4; ++r) {
      float mn = fmaxf(mrow[r], mt[r]);
      corr[r] = __expf(mrow[r] - mn);
      mrow[r] = mn;
    }

    float psum[4] = {0.f, 0.f, 0.f, 0.f};
#pragma unroll
    for (int nf = 0; nf < 4; ++nf)
#pragma unroll
      for (int r = 0; r < 4; ++r) {
        float p = __expf(sacc[nf][r] - mrow[r]);
        psum[r] += p;
        int row = g * 4 + r, col = nf * 16 + lr;
        *(f16*)(Pw + row * 128 + (((col >> 3) ^ (row & 7)) * 16) + (col & 7) * 2) = (f16)p;
      }
#pragma unroll
    for (int d = 1; d < 16; d <<= 1)
#pragma unroll
      for (int r = 0; r < 4; ++r) psum[r] += __shfl_xor(psum[r], d);
#pragma unroll
    for (int r = 0; r < 4; ++r) lrow[r] = lrow[r] * corr[r] + psum[r];
#pragma unroll
    for (int df = 0; df < 4; ++df)
#pragma unroll
      for (int r = 0; r < 4; ++r) oacc[df][r] *= corr[r];

    asm volatile("s_waitcnt lgkmcnt(0)" ::: "memory");

#pragma unroll
    for (int ks = 0; ks < 2; ++ks) {
      f16x8 pf = *(const f16x8*)(Pw + lr * 128 + (((g + 4 * ks) ^ (lr & 7)) * 16));
#pragma unroll
      for (int df = 0; df < 4; ++df) {
        int row = df * 16 + lr;
        int slot = (g + 4 * ks) ^ (row & 7);
        f16x8 vf = *(const f16x8*)((const char*)Vs + row * 128 + slot * 16);
        oacc[df] = __builtin_amdgcn_mfma_f32_16x16x32_f16(pf, vf, oacc[df], 0, 0, 0);
      }
    }
  }

#pragma unroll
  for (int df = 0; df < 4; ++df)
#pragma unroll
    for (int r = 0; r < 4; ++r) {
      size_t rowg = (size_t)(b * SEQ + q0 + w * 16 + g * 4 + r);
      AO[rowg * HID + h * 64 + df * 16 + lr] = (f16)(oacc[df][r] / lrow[r]);
    }
}

// ---------------- launch ----------------
extern "C" void kernel_launch(void* const* d_in, const int* in_sizes, int n_in,
                              void* d_out, int out_size, void* d_ws, size_t ws_size,
                              hipStream_t stream) {
  const float* X  = (const float*)d_in[0];
  const float* Wq = (const float*)d_in[1];
  const float* Wk = (const float*)d_in[2];
  const float* Wv = (const float*)d_in[3];
  const float* Wo = (const float*)d_in[4];
  const float* qw = (const float*)d_in[5];
  const float* kw = (const float*)d_in[6];

  char* ws = (char*)d_ws;
  f16* Xb   = (f16*)(ws + 0);           // 4096 x 2048
  f16* Wqb  = (f16*)(ws + 16777216);    // 2048 x 2048
  f16* Wkvb = (f16*)(ws + 25165824);    // 1024 x 2048 (Wk rows then Wv rows)
  f16* Wob  = (f16*)(ws + 29360128);    // 2048 x 2048
  f16* Qb   = (f16*)(ws + 37748736);    // 4096 x 2048
  f16* KVb  = (f16*)(ws + 54525952);    // 4096 x 1024 (K cols 0..511, V cols 512..1023)
  f16* VTb  = (f16*)(ws + 62914560);    // [2][8][64][2048]
  f16* AOb  = (f16*)(ws + 67108864);    // 4096 x 2048
  float* OUT = (float*)d_out;

  cvt_f16<<<8192, 256, 0, stream>>>(X, Xb, 2097152);
  cvt_f16<<<4096, 256, 0, stream>>>(Wq, Wqb, 1048576);
  cvt_f16<<<1024, 256, 0, stream>>>(Wk, Wkvb, 262144);
  cvt_f16<<<1024, 256, 0, stream>>>(Wv, Wkvb + 512 * 2048, 262144);
  cvt_f16<<<4096, 256, 0, stream>>>(Wo, Wob, 1048576);

  gemm_bt<f16><<<dim3(16, 32), 256, 0, stream>>>(Xb, Wqb, Qb, 4096, 2048, 2048);
  gemm_bt<f16><<<dim3(8, 32), 256, 0, stream>>>(Xb, Wkvb, KVb, 4096, 1024, 2048);

  rmsnorm64<<<32768, 256, 0, stream>>>(Qb, qw, 32, 2048, 131072, 0.125f);
  rmsnorm64<<<8192, 256, 0, stream>>>(KVb, kw, 8, 1024, 32768, 1.0f);

  vtrans<<<dim3(32, 8, 2), 256, 0, stream>>>(KVb, VTb);
  attn<<<dim3(32, 32, 2), 256, 0, stream>>>(Qb, KVb, VTb, AOb);

  gemm_bt<float><<<dim3(16, 32), 256, 0, stream>>>(AOb, Wob, OUT, 4096, 2048, 2048);
}

// Round 2
// 286.025 us; speedup vs baseline: 1.4278x; 1.4278x over previous
//
#include <hip/hip_runtime.h>

typedef _Float16 f16;
typedef _Float16 f16x8 __attribute__((ext_vector_type(8)));
typedef _Float16 f16x4 __attribute__((ext_vector_type(4)));
typedef float f32x4 __attribute__((ext_vector_type(4)));

#define HID 2048
#define NH 32
#define NKV 8
#define HD 64
#define SEQ 2048
#define NB 2

__device__ __forceinline__ void gload_lds16(const void* g, void* l) {
  __builtin_amdgcn_global_load_lds((const __attribute__((address_space(1))) void*)g,
                                   (__attribute__((address_space(3))) void*)l, 16, 0, 0);
}

// ---------------- f32 -> f16 convert ----------------
__global__ __launch_bounds__(256) void cvt_f16(const float* __restrict__ in,
                                               f16* __restrict__ out, int n4) {
  int i = blockIdx.x * 256 + threadIdx.x;
  if (i < n4) {
    float4 v = ((const float4*)in)[i];
    f16x4 o = { (f16)v.x, (f16)v.y, (f16)v.z, (f16)v.w };
    ((f16x4*)out)[i] = o;
  }
}

// ---------------- GEMM: C[M,N] = A[M,K] * B[N,K]^T ----------------
// 128x128 tile, BK=64, 4 waves (2x2 of 64x64), 16x16x32 f16 MFMA.
// LDS double-buffered, global_load_lds w/ pre-swizzled source (slot ^= row&7).
template <typename CT>
__global__ __launch_bounds__(256) void gemm_bt(const f16* __restrict__ A,
                                               const f16* __restrict__ Bm,
                                               CT* __restrict__ C,
                                               int M, int N, int K) {
  __shared__ f16 As[2][128 * 64];
  __shared__ f16 Bs[2][128 * 64];
  const int t = threadIdx.x;
  const int lane = t & 63;
  const int w = t >> 6;
  const int wr = w >> 1, wc = w & 1;
  const int g = lane >> 4;
  const int lr = lane & 15;
  const int m0 = blockIdx.y * 128;
  const int n0 = blockIdx.x * 128;

  f32x4 acc[4][4] = {};

  const int nkt = K / 64;

  auto stage = [&](int buf, int kt) {
    const int k0 = kt * 64;
#pragma unroll
    for (int i = 0; i < 4; ++i) {
      int c = w * 4 + i;
      int o = c * 1024 + lane * 16;
      int row = o >> 7;
      int ss = ((o >> 4) & 7) ^ (row & 7);
      const char* srcA = (const char*)A + ((size_t)(m0 + row) * K + k0) * 2 + ss * 16;
      gload_lds16(srcA, (char*)(&As[buf][0]) + c * 1024);
      const char* srcB = (const char*)Bm + ((size_t)(n0 + row) * K + k0) * 2 + ss * 16;
      gload_lds16(srcB, (char*)(&Bs[buf][0]) + c * 1024);
    }
  };

  stage(0, 0);
  __syncthreads();
  int cur = 0;
  for (int kt = 0; kt < nkt; ++kt) {
    if (kt + 1 < nkt) stage(cur ^ 1, kt + 1);
#pragma unroll
    for (int ks = 0; ks < 2; ++ks) {
      f16x8 af[4], bf[4];
#pragma unroll
      for (int mf = 0; mf < 4; ++mf) {
        int row = wr * 64 + mf * 16 + lr;
        int slot = (g + 4 * ks) ^ (row & 7);
        af[mf] = *(const f16x8*)((const char*)(&As[cur][0]) + row * 128 + slot * 16);
      }
#pragma unroll
      for (int nf = 0; nf < 4; ++nf) {
        int row = wc * 64 + nf * 16 + lr;
        int slot = (g + 4 * ks) ^ (row & 7);
        bf[nf] = *(const f16x8*)((const char*)(&Bs[cur][0]) + row * 128 + slot * 16);
      }
#pragma unroll
      for (int mf = 0; mf < 4; ++mf)
#pragma unroll
        for (int nf = 0; nf < 4; ++nf)
          acc[mf][nf] = __builtin_amdgcn_mfma_f32_16x16x32_f16(af[mf], bf[nf], acc[mf][nf], 0, 0, 0);
    }
    __syncthreads();
    cur ^= 1;
  }

#pragma unroll
  for (int mf = 0; mf < 4; ++mf)
#pragma unroll
    for (int nf = 0; nf < 4; ++nf)
#pragma unroll
      for (int r = 0; r < 4; ++r) {
        int mm = m0 + wr * 64 + mf * 16 + g * 4 + r;
        int nn = n0 + wc * 64 + nf * 16 + lr;
        C[(size_t)mm * N + nn] = (CT)acc[mf][nf][r];
      }
}

// ---------------- RMSNorm over 64-elem head rows (in place) ----------------
__global__ __launch_bounds__(256) void rmsnorm64(f16* __restrict__ p,
                                                 const float* __restrict__ w,
                                                 int heads_per_row, int row_stride,
                                                 int total_chunks, float extra) {
  int c = blockIdx.x * 4 + (threadIdx.x >> 6);
  int lane = threadIdx.x & 63;
  if (c >= total_chunks) return;
  int m = c / heads_per_row, hh = c % heads_per_row;
  f16* base = p + (size_t)m * row_stride + hh * 64;
  float x = (float)base[lane];
  float ss = x * x;
#pragma unroll
  for (int d = 1; d < 64; d <<= 1) ss += __shfl_xor(ss, d);
  float sc = rsqrtf(ss * (1.0f / 64.0f) + 1e-6f) * extra;
  base[lane] = (f16)(x * sc * w[lane]);
}

// ---------------- V transpose: KV[:,512:] -> VT[b][hk][d][s] ----------------
__global__ __launch_bounds__(256) void vtrans(const f16* __restrict__ KV,
                                              f16* __restrict__ VT) {
  __shared__ f16 tile[64][72];
  int t = threadIdx.x;
  int st = blockIdx.x, hk = blockIdx.y, b = blockIdx.z;
#pragma unroll
  for (int p = 0; p < 2; ++p) {
    int idx = p * 256 + t;
    int s = idx >> 3, c8 = (idx & 7) * 8;
    f16x8 v = *(const f16x8*)(KV + (size_t)(b * SEQ + st * 64 + s) * 1024 + 512 + hk * 64 + c8);
    *(f16x8*)(&tile[s][c8]) = v;
  }
  __syncthreads();
#pragma unroll
  for (int p = 0; p < 2; ++p) {
    int idx = p * 256 + t;
    int d = idx >> 3, s8 = (idx & 7) * 8;
    f16x8 ov;
#pragma unroll
    for (int j = 0; j < 8; ++j) ov[j] = tile[s8 + j][d];
    *(f16x8*)(VT + ((size_t)((b * NKV + hk) * 64) + d) * SEQ + st * 64 + s8) = ov;
  }
}

// ---------------- causal GQA flash attention ----------------
// block = (qt, h, b); 4 waves x 16 q-rows; KV tile 64.
// Fixed-max softmax: RMSNorm guarantees s = q.k/8 in [-8, 8], so P = exp(s)
// fits f16 ([3.3e-4, 2981]) with no running max, no rescale. Row-sum
// accumulates per-lane; reduced once at the end.
// Double-buffered K/V staging, one barrier per KV tile; qt reversed for LPT.
__global__ __launch_bounds__(256) void attn(const f16* __restrict__ Q,
                                            const f16* __restrict__ KV,
                                            const f16* __restrict__ VT,
                                            f16* __restrict__ AO) {
  __shared__ f16 Ks[2][64 * 64];   // [kv][d], slot-swizzled
  __shared__ f16 Vs[2][64 * 64];   // V^T: [d][kv], slot-swizzled
  __shared__ f16 Ps[4][16 * 64];
  const int t = threadIdx.x, lane = t & 63, w = t >> 6;
  const int g = lane >> 4, lr = lane & 15;
  const int qt = 31 - blockIdx.x;  // longest blocks first (LPT)
  const int h = blockIdx.y, b = blockIdx.z;
  const int hk = h >> 2;
  const int q0 = qt * 64;

  const size_t qrow = (size_t)(b * SEQ + q0 + w * 16 + lr);
  f16x8 qf[2];
  qf[0] = *(const f16x8*)(Q + qrow * HID + h * 64 + g * 8);
  qf[1] = *(const f16x8*)(Q + qrow * HID + h * 64 + g * 8 + 32);

  f32x4 oacc[4] = {};
  f32x4 psum = {0.f, 0.f, 0.f, 0.f};

  char* Pw = (char*)(&Ps[w][0]);
  const int nkt = qt + 1;

  auto stage = [&](int buf, int kt) {
#pragma unroll
    for (int i = 0; i < 2; ++i) {
      int c = w * 2 + i;
      int o = c * 1024 + lane * 16;
      int row = o >> 7;
      int ss = ((o >> 4) & 7) ^ (row & 7);
      gload_lds16((const char*)KV + ((size_t)(b * SEQ + kt * 64 + row) * 1024 + hk * 64) * 2 + ss * 16,
                  (char*)(&Ks[buf][0]) + c * 1024);
      gload_lds16((const char*)VT + (((size_t)((b * NKV + hk) * 64) + row) * SEQ + kt * 64) * 2 + ss * 16,
                  (char*)(&Vs[buf][0]) + c * 1024);
    }
  };

  stage(0, 0);
  __syncthreads();
  int cur = 0;
  for (int kt = 0; kt < nkt; ++kt) {
    if (kt + 1 < nkt) stage(cur ^ 1, kt + 1);

    // S = Q K^T (1/8 scale folded into Q by rmsnorm)
    f32x4 sacc[4] = {};
#pragma unroll
    for (int ks = 0; ks < 2; ++ks) {
      f16x8 kf[4];
#pragma unroll
      for (int nf = 0; nf < 4; ++nf) {
        int row = nf * 16 + lr;
        int slot = (g + 4 * ks) ^ (row & 7);
        kf[nf] = *(const f16x8*)((const char*)(&Ks[cur][0]) + row * 128 + slot * 16);
      }
#pragma unroll
      for (int nf = 0; nf < 4; ++nf)
        sacc[nf] = __builtin_amdgcn_mfma_f32_16x16x32_f16(qf[ks], kf[nf], sacc[nf], 0, 0, 0);
    }

    if (kt == qt) {
#pragma unroll
      for (int nf = 0; nf < 4; ++nf) {
        int kv = kt * 64 + nf * 16 + lr;
#pragma unroll
        for (int r = 0; r < 4; ++r) {
          int qq = q0 + w * 16 + g * 4 + r;
          if (kv > qq) sacc[nf][r] = -1e30f;
        }
      }
    }

    // P = exp(s); per-lane partial row-sum; store P^T fragment to LDS
#pragma unroll
    for (int nf = 0; nf < 4; ++nf)
#pragma unroll
      for (int r = 0; r < 4; ++r) {
        float p = __expf(sacc[nf][r]);
        psum[r] += p;
        int row = g * 4 + r, col = nf * 16 + lr;
        *(f16*)(Pw + row * 128 + (((col >> 3) ^ (row & 7)) * 16) + (col & 7) * 2) = (f16)p;
      }

    asm volatile("s_waitcnt lgkmcnt(0)" ::: "memory");

    // O += P V
#pragma unroll
    for (int ks = 0; ks < 2; ++ks) {
      f16x8 pf = *(const f16x8*)(Pw + lr * 128 + (((g + 4 * ks) ^ (lr & 7)) * 16));
#pragma unroll
      for (int df = 0; df < 4; ++df) {
        int row = df * 16 + lr;
        int slot = (g + 4 * ks) ^ (row & 7);
        f16x8 vf = *(const f16x8*)((const char*)(&Vs[cur][0]) + row * 128 + slot * 16);
        oacc[df] = __builtin_amdgcn_mfma_f32_16x16x32_f16(pf, vf, oacc[df], 0, 0, 0);
      }
    }

    __syncthreads();
    cur ^= 1;
  }

  // one final row-sum reduce across the 16-lane lr group
#pragma unroll
  for (int d = 1; d < 16; d <<= 1)
#pragma unroll
    for (int r = 0; r < 4; ++r) psum[r] += __shfl_xor(psum[r], d);

#pragma unroll
  for (int df = 0; df < 4; ++df)
#pragma unroll
    for (int r = 0; r < 4; ++r) {
      size_t rowg = (size_t)(b * SEQ + q0 + w * 16 + g * 4 + r);
      AO[rowg * HID + h * 64 + df * 16 + lr] = (f16)(oacc[df][r] / psum[r]);
    }
}

// ---------------- launch ----------------
extern "C" void kernel_launch(void* const* d_in, const int* in_sizes, int n_in,
                              void* d_out, int out_size, void* d_ws, size_t ws_size,
                              hipStream_t stream) {
  const float* X  = (const float*)d_in[0];
  const float* Wq = (const float*)d_in[1];
  const float* Wk = (const float*)d_in[2];
  const float* Wv = (const float*)d_in[3];
  const float* Wo = (const float*)d_in[4];
  const float* qw = (const float*)d_in[5];
  const float* kw = (const float*)d_in[6];

  char* ws = (char*)d_ws;
  f16* Xb   = (f16*)(ws + 0);           // 4096 x 2048
  f16* Wqb  = (f16*)(ws + 16777216);    // 2048 x 2048
  f16* Wkvb = (f16*)(ws + 25165824);    // 1024 x 2048 (Wk rows then Wv rows)
  f16* Wob  = (f16*)(ws + 29360128);    // 2048 x 2048
  f16* Qb   = (f16*)(ws + 37748736);    // 4096 x 2048
  f16* KVb  = (f16*)(ws + 54525952);    // 4096 x 1024 (K cols 0..511, V cols 512..1023)
  f16* VTb  = (f16*)(ws + 62914560);    // [2][8][64][2048]
  f16* AOb  = (f16*)(ws + 67108864);    // 4096 x 2048
  float* OUT = (float*)d_out;

  cvt_f16<<<8192, 256, 0, stream>>>(X, Xb, 2097152);
  cvt_f16<<<4096, 256, 0, stream>>>(Wq, Wqb, 1048576);
  cvt_f16<<<1024, 256, 0, stream>>>(Wk, Wkvb, 262144);
  cvt_f16<<<1024, 256, 0, stream>>>(Wv, Wkvb + 512 * 2048, 262144);
  cvt_f16<<<4096, 256, 0, stream>>>(Wo, Wob, 1048576);

  gemm_bt<f16><<<dim3(16, 32), 256, 0, stream>>>(Xb, Wqb, Qb, 4096, 2048, 2048);
  gemm_bt<f16><<<dim3(8, 32), 256, 0, stream>>>(Xb, Wkvb, KVb, 4096, 1024, 2048);

  rmsnorm64<<<32768, 256, 0, stream>>>(Qb, qw, 32, 2048, 131072, 0.125f);
  rmsnorm64<<<8192, 256, 0, stream>>>(KVb, kw, 8, 1024, 32768, 1.0f);

  vtrans<<<dim3(32, 8, 2), 256, 0, stream>>>(KVb, VTb);
  attn<<<dim3(32, 32, 2), 256, 0, stream>>>(Qb, KVb, VTb, AOb);

  gemm_bt<float><<<dim3(16, 32), 256, 0, stream>>>(AOb, Wob, OUT, 4096, 2048, 2048);
}

// Round 3
// 283.866 us; speedup vs baseline: 1.4387x; 1.0076x over previous
//
#include <hip/hip_runtime.h>

typedef _Float16 f16;
typedef _Float16 f16x8 __attribute__((ext_vector_type(8)));
typedef _Float16 f16x4 __attribute__((ext_vector_type(4)));
typedef float f32x4 __attribute__((ext_vector_type(4)));

#define HID 2048
#define NH 32
#define NKV 8
#define HD 64
#define SEQ 2048
#define NB 2

__device__ __forceinline__ void gload_lds16(const void* g, void* l) {
  __builtin_amdgcn_global_load_lds((const __attribute__((address_space(1))) void*)g,
                                   (__attribute__((address_space(3))) void*)l, 16, 0, 0);
}

// ---------------- f32 -> f16 convert ----------------
__global__ __launch_bounds__(256) void cvt_f16(const float* __restrict__ in,
                                               f16* __restrict__ out, int n4) {
  int i = blockIdx.x * 256 + threadIdx.x;
  if (i < n4) {
    float4 v = ((const float4*)in)[i];
    f16x4 o = { (f16)v.x, (f16)v.y, (f16)v.z, (f16)v.w };
    ((f16x4*)out)[i] = o;
  }
}

// ---------------- GEMM: C[M,N] = A[M,K] * B[N,K]^T ----------------
// 128x128 tile, BK=64, 4 waves (2x2 of 64x64), 16x16x32 f16 MFMA.
// LDS double-buffered, global_load_lds w/ pre-swizzled source (slot ^= row&7).
// T1: XCD-aware block swizzle (requires nwg % 8 == 0 — all our grids comply).
template <typename CT>
__global__ __launch_bounds__(256) void gemm_bt(const f16* __restrict__ A,
                                               const f16* __restrict__ Bm,
                                               CT* __restrict__ C,
                                               int M, int N, int K) {
  __shared__ f16 As[2][128 * 64];
  __shared__ f16 Bs[2][128 * 64];
  const int t = threadIdx.x;
  const int lane = t & 63;
  const int w = t >> 6;
  const int wr = w >> 1, wc = w & 1;
  const int g = lane >> 4;
  const int lr = lane & 15;

  const int nwg = gridDim.x * gridDim.y;
  const int orig = blockIdx.y * gridDim.x + blockIdx.x;
  const int wg = (orig & 7) * (nwg >> 3) + (orig >> 3);
  const int m0 = (wg / gridDim.x) * 128;
  const int n0 = (wg % gridDim.x) * 128;

  f32x4 acc[4][4] = {};

  const int nkt = K / 64;

  auto stage = [&](int buf, int kt) {
    const int k0 = kt * 64;
#pragma unroll
    for (int i = 0; i < 4; ++i) {
      int c = w * 4 + i;
      int o = c * 1024 + lane * 16;
      int row = o >> 7;
      int ss = ((o >> 4) & 7) ^ (row & 7);
      const char* srcA = (const char*)A + ((size_t)(m0 + row) * K + k0) * 2 + ss * 16;
      gload_lds16(srcA, (char*)(&As[buf][0]) + c * 1024);
      const char* srcB = (const char*)Bm + ((size_t)(n0 + row) * K + k0) * 2 + ss * 16;
      gload_lds16(srcB, (char*)(&Bs[buf][0]) + c * 1024);
    }
  };

  stage(0, 0);
  __syncthreads();
  int cur = 0;
  for (int kt = 0; kt < nkt; ++kt) {
    if (kt + 1 < nkt) stage(cur ^ 1, kt + 1);
#pragma unroll
    for (int ks = 0; ks < 2; ++ks) {
      f16x8 af[4], bf[4];
#pragma unroll
      for (int mf = 0; mf < 4; ++mf) {
        int row = wr * 64 + mf * 16 + lr;
        int slot = (g + 4 * ks) ^ (row & 7);
        af[mf] = *(const f16x8*)((const char*)(&As[cur][0]) + row * 128 + slot * 16);
      }
#pragma unroll
      for (int nf = 0; nf < 4; ++nf) {
        int row = wc * 64 + nf * 16 + lr;
        int slot = (g + 4 * ks) ^ (row & 7);
        bf[nf] = *(const f16x8*)((const char*)(&Bs[cur][0]) + row * 128 + slot * 16);
      }
      __builtin_amdgcn_s_setprio(1);
#pragma unroll
      for (int mf = 0; mf < 4; ++mf)
#pragma unroll
        for (int nf = 0; nf < 4; ++nf)
          acc[mf][nf] = __builtin_amdgcn_mfma_f32_16x16x32_f16(af[mf], bf[nf], acc[mf][nf], 0, 0, 0);
      __builtin_amdgcn_s_setprio(0);
    }
    __syncthreads();
    cur ^= 1;
  }

#pragma unroll
  for (int mf = 0; mf < 4; ++mf)
#pragma unroll
    for (int nf = 0; nf < 4; ++nf)
#pragma unroll
      for (int r = 0; r < 4; ++r) {
        int mm = m0 + wr * 64 + mf * 16 + g * 4 + r;
        int nn = n0 + wc * 64 + nf * 16 + lr;
        C[(size_t)mm * N + nn] = (CT)acc[mf][nf][r];
      }
}

// ---------------- RMSNorm over 64-elem head rows (in place) ----------------
__global__ __launch_bounds__(256) void rmsnorm64(f16* __restrict__ p,
                                                 const float* __restrict__ w,
                                                 int heads_per_row, int row_stride,
                                                 int total_chunks, float extra) {
  int c = blockIdx.x * 4 + (threadIdx.x >> 6);
  int lane = threadIdx.x & 63;
  if (c >= total_chunks) return;
  int m = c / heads_per_row, hh = c % heads_per_row;
  f16* base = p + (size_t)m * row_stride + hh * 64;
  float x = (float)base[lane];
  float ss = x * x;
#pragma unroll
  for (int d = 1; d < 64; d <<= 1) ss += __shfl_xor(ss, d);
  float sc = rsqrtf(ss * (1.0f / 64.0f) + 1e-6f) * extra;
  base[lane] = (f16)(x * sc * w[lane]);
}

// ---------------- V transpose: KV[:,512:] -> VT[b][hk][d][s] ----------------
__global__ __launch_bounds__(256) void vtrans(const f16* __restrict__ KV,
                                              f16* __restrict__ VT) {
  __shared__ f16 tile[64][72];
  int t = threadIdx.x;
  int st = blockIdx.x, hk = blockIdx.y, b = blockIdx.z;
#pragma unroll
  for (int p = 0; p < 2; ++p) {
    int idx = p * 256 + t;
    int s = idx >> 3, c8 = (idx & 7) * 8;
    f16x8 v = *(const f16x8*)(KV + (size_t)(b * SEQ + st * 64 + s) * 1024 + 512 + hk * 64 + c8);
    *(f16x8*)(&tile[s][c8]) = v;
  }
  __syncthreads();
#pragma unroll
  for (int p = 0; p < 2; ++p) {
    int idx = p * 256 + t;
    int d = idx >> 3, s8 = (idx & 7) * 8;
    f16x8 ov;
#pragma unroll
    for (int j = 0; j < 8; ++j) ov[j] = tile[s8 + j][d];
    *(f16x8*)(VT + ((size_t)((b * NKV + hk) * 64) + d) * SEQ + st * 64 + s8) = ov;
  }
}

// ---------------- causal GQA flash attention ----------------
// block = (qt, h, b); QBLK=128: 4 waves x 32 q-rows (2 fragments), KV tile 64.
// Fixed-max softmax (RMSNorm bounds s in [-8,8] -> P=exp(s) fits f16; no
// running max, no rescale; per-lane row-sum reduced once at the end).
// Double-buffered K/V, one barrier per KV tile, LPT (qt reversed), T5 setprio.
__global__ __launch_bounds__(256) void attn(const f16* __restrict__ Q,
                                            const f16* __restrict__ KV,
                                            const f16* __restrict__ VT,
                                            f16* __restrict__ AO) {
  __shared__ f16 Ks[2][64 * 64];   // [kv][d], slot-swizzled
  __shared__ f16 Vs[2][64 * 64];   // V^T: [d][kv], slot-swizzled
  __shared__ f16 Ps[4][32 * 64];   // per-wave P, 32 q-rows
  const int t = threadIdx.x, lane = t & 63, w = t >> 6;
  const int g = lane >> 4, lr = lane & 15;
  const int qt = 15 - blockIdx.x;  // longest blocks first (LPT)
  const int h = blockIdx.y, b = blockIdx.z;
  const int hk = h >> 2;
  const int q0 = qt * 128;

  f16x8 qf[2][2];
#pragma unroll
  for (int f = 0; f < 2; ++f) {
    const size_t qrow = (size_t)(b * SEQ + q0 + w * 32 + f * 16 + lr);
    qf[f][0] = *(const f16x8*)(Q + qrow * HID + h * 64 + g * 8);
    qf[f][1] = *(const f16x8*)(Q + qrow * HID + h * 64 + g * 8 + 32);
  }

  f32x4 oacc[2][4] = {};
  f32x4 psum[2] = {};

  char* Pw = (char*)(&Ps[w][0]);
  const int nkt = 2 * qt + 2;

  auto stage = [&](int buf, int kt) {
#pragma unroll
    for (int i = 0; i < 2; ++i) {
      int c = w * 2 + i;
      int o = c * 1024 + lane * 16;
      int row = o >> 7;
      int ss = ((o >> 4) & 7) ^ (row & 7);
      gload_lds16((const char*)KV + ((size_t)(b * SEQ + kt * 64 + row) * 1024 + hk * 64) * 2 + ss * 16,
                  (char*)(&Ks[buf][0]) + c * 1024);
      gload_lds16((const char*)VT + (((size_t)((b * NKV + hk) * 64) + row) * SEQ + kt * 64) * 2 + ss * 16,
                  (char*)(&Vs[buf][0]) + c * 1024);
    }
  };

  stage(0, 0);
  __syncthreads();
  int cur = 0;
  for (int kt = 0; kt < nkt; ++kt) {
    if (kt + 1 < nkt) stage(cur ^ 1, kt + 1);

    // S = Q K^T (1/8 scale folded into Q by rmsnorm)
    f32x4 sacc[2][4] = {};
#pragma unroll
    for (int ks = 0; ks < 2; ++ks) {
      f16x8 kf[4];
#pragma unroll
      for (int nf = 0; nf < 4; ++nf) {
        int row = nf * 16 + lr;
        int slot = (g + 4 * ks) ^ (row & 7);
        kf[nf] = *(const f16x8*)((const char*)(&Ks[cur][0]) + row * 128 + slot * 16);
      }
      __builtin_amdgcn_s_setprio(1);
#pragma unroll
      for (int f = 0; f < 2; ++f)
#pragma unroll
        for (int nf = 0; nf < 4; ++nf)
          sacc[f][nf] = __builtin_amdgcn_mfma_f32_16x16x32_f16(qf[f][ks], kf[nf], sacc[f][nf], 0, 0, 0);
      __builtin_amdgcn_s_setprio(0);
    }

    if (kt >= 2 * qt) {  // possibly-diagonal tiles
#pragma unroll
      for (int f = 0; f < 2; ++f)
#pragma unroll
        for (int nf = 0; nf < 4; ++nf) {
          int kv = kt * 64 + nf * 16 + lr;
#pragma unroll
          for (int r = 0; r < 4; ++r) {
            int qq = q0 + w * 32 + f * 16 + g * 4 + r;
            if (kv > qq) sacc[f][nf][r] = -1e30f;
          }
        }
    }

    // P = exp(s); per-lane partial row-sum; store P^T fragment to LDS
#pragma unroll
    for (int f = 0; f < 2; ++f)
#pragma unroll
      for (int nf = 0; nf < 4; ++nf)
#pragma unroll
        for (int r = 0; r < 4; ++r) {
          float p = __expf(sacc[f][nf][r]);
          psum[f][r] += p;
          int row = f * 16 + g * 4 + r, col = nf * 16 + lr;
          *(f16*)(Pw + row * 128 + (((col >> 3) ^ (row & 7)) * 16) + (col & 7) * 2) = (f16)p;
        }

    asm volatile("s_waitcnt lgkmcnt(0)" ::: "memory");

    // O += P V
#pragma unroll
    for (int ks = 0; ks < 2; ++ks) {
      f16x8 pf[2];
#pragma unroll
      for (int f = 0; f < 2; ++f) {
        int prow = f * 16 + lr;
        pf[f] = *(const f16x8*)(Pw + prow * 128 + (((g + 4 * ks) ^ (prow & 7)) * 16));
      }
      f16x8 vf[4];
#pragma unroll
      for (int df = 0; df < 4; ++df) {
        int row = df * 16 + lr;
        int slot = (g + 4 * ks) ^ (row & 7);
        vf[df] = *(const f16x8*)((const char*)(&Vs[cur][0]) + row * 128 + slot * 16);
      }
      __builtin_amdgcn_s_setprio(1);
#pragma unroll
      for (int f = 0; f < 2; ++f)
#pragma unroll
        for (int df = 0; df < 4; ++df)
          oacc[f][df] = __builtin_amdgcn_mfma_f32_16x16x32_f16(pf[f], vf[df], oacc[f][df], 0, 0, 0);
      __builtin_amdgcn_s_setprio(0);
    }

    __syncthreads();
    cur ^= 1;
  }

  // one final row-sum reduce across the 16-lane lr group
#pragma unroll
  for (int d = 1; d < 16; d <<= 1)
#pragma unroll
    for (int f = 0; f < 2; ++f)
#pragma unroll
      for (int r = 0; r < 4; ++r) psum[f][r] += __shfl_xor(psum[f][r], d);

#pragma unroll
  for (int f = 0; f < 2; ++f)
#pragma unroll
    for (int df = 0; df < 4; ++df)
#pragma unroll
      for (int r = 0; r < 4; ++r) {
        size_t rowg = (size_t)(b * SEQ + q0 + w * 32 + f * 16 + g * 4 + r);
        AO[rowg * HID + h * 64 + df * 16 + lr] = (f16)(oacc[f][df][r] / psum[f][r]);
      }
}

// ---------------- launch ----------------
extern "C" void kernel_launch(void* const* d_in, const int* in_sizes, int n_in,
                              void* d_out, int out_size, void* d_ws, size_t ws_size,
                              hipStream_t stream) {
  const float* X  = (const float*)d_in[0];
  const float* Wq = (const float*)d_in[1];
  const float* Wk = (const float*)d_in[2];
  const float* Wv = (const float*)d_in[3];
  const float* Wo = (const float*)d_in[4];
  const float* qw = (const float*)d_in[5];
  const float* kw = (const float*)d_in[6];

  char* ws = (char*)d_ws;
  f16* Xb   = (f16*)(ws + 0);           // 4096 x 2048
  f16* Wqb  = (f16*)(ws + 16777216);    // 2048 x 2048
  f16* Wkvb = (f16*)(ws + 25165824);    // 1024 x 2048 (Wk rows then Wv rows)
  f16* Wob  = (f16*)(ws + 29360128);    // 2048 x 2048
  f16* Qb   = (f16*)(ws + 37748736);    // 4096 x 2048
  f16* KVb  = (f16*)(ws + 54525952);    // 4096 x 1024 (K cols 0..511, V cols 512..1023)
  f16* VTb  = (f16*)(ws + 62914560);    // [2][8][64][2048]
  f16* AOb  = (f16*)(ws + 67108864);    // 4096 x 2048
  float* OUT = (float*)d_out;

  cvt_f16<<<8192, 256, 0, stream>>>(X, Xb, 2097152);
  cvt_f16<<<4096, 256, 0, stream>>>(Wq, Wqb, 1048576);
  cvt_f16<<<1024, 256, 0, stream>>>(Wk, Wkvb, 262144);
  cvt_f16<<<1024, 256, 0, stream>>>(Wv, Wkvb + 512 * 2048, 262144);
  cvt_f16<<<4096, 256, 0, stream>>>(Wo, Wob, 1048576);

  gemm_bt<f16><<<dim3(16, 32), 256, 0, stream>>>(Xb, Wqb, Qb, 4096, 2048, 2048);
  gemm_bt<f16><<<dim3(8, 32), 256, 0, stream>>>(Xb, Wkvb, KVb, 4096, 1024, 2048);

  rmsnorm64<<<32768, 256, 0, stream>>>(Qb, qw, 32, 2048, 131072, 0.125f);
  rmsnorm64<<<8192, 256, 0, stream>>>(KVb, kw, 8, 1024, 32768, 1.0f);

  vtrans<<<dim3(32, 8, 2), 256, 0, stream>>>(KVb, VTb);
  attn<<<dim3(16, 32, 2), 256, 0, stream>>>(Qb, KVb, VTb, AOb);

  gemm_bt<float><<<dim3(16, 32), 256, 0, stream>>>(AOb, Wob, OUT, 4096, 2048, 2048);
}

// Round 4
// 253.529 us; speedup vs baseline: 1.6108x; 1.1197x over previous
//
#include <hip/hip_runtime.h>

typedef _Float16 f16;
typedef _Float16 f16x8 __attribute__((ext_vector_type(8)));
typedef _Float16 f16x4 __attribute__((ext_vector_type(4)));
typedef float f32x4 __attribute__((ext_vector_type(4)));

#define HID 2048
#define NH 32
#define NKV 8
#define HD 64
#define SEQ 2048
#define NB 2

__device__ __forceinline__ void gload_lds16(const void* g, void* l) {
  __builtin_amdgcn_global_load_lds((const __attribute__((address_space(1))) void*)g,
                                   (__attribute__((address_space(3))) void*)l, 16, 0, 0);
}

// ---------------- fused f32 -> f16 convert of all 5 tensors ----------------
__global__ __launch_bounds__(256) void cvt_all(const float* __restrict__ X,
                                               const float* __restrict__ Wq,
                                               const float* __restrict__ Wk,
                                               const float* __restrict__ Wv,
                                               const float* __restrict__ Wo,
                                               f16* __restrict__ Xb, f16* __restrict__ Wqb,
                                               f16* __restrict__ Wkb, f16* __restrict__ Wvb,
                                               f16* __restrict__ Wob) {
  long i = (long)blockIdx.x * 256 + threadIdx.x;
  const float* s; f16* d; long o;
  if (i < 2097152)      { s = X;  d = Xb;  o = i; }
  else if (i < 3145728) { s = Wq; d = Wqb; o = i - 2097152; }
  else if (i < 3407872) { s = Wk; d = Wkb; o = i - 3145728; }
  else if (i < 3670016) { s = Wv; d = Wvb; o = i - 3407872; }
  else                  { s = Wo; d = Wob; o = i - 3670016; }
  float4 v = ((const float4*)s)[o];
  f16x4 ov = { (f16)v.x, (f16)v.y, (f16)v.z, (f16)v.w };
  ((f16x4*)d)[o] = ov;
}

// ---------------- GEMM: C[M,N] = A[M,K] * B[N,K]^T ----------------
// 128x128 tile, BK=64, 4 waves (2x2 of 64x64), 16x16x32 f16 MFMA.
// LDS dbuf, global_load_lds w/ pre-swizzled source, T1 XCD swizzle, T5 setprio.
template <typename CT>
__global__ __launch_bounds__(256) void gemm_bt(const f16* __restrict__ A,
                                               const f16* __restrict__ Bm,
                                               CT* __restrict__ C,
                                               int M, int N, int K) {
  __shared__ f16 As[2][128 * 64];
  __shared__ f16 Bs[2][128 * 64];
  const int t = threadIdx.x;
  const int lane = t & 63;
  const int w = t >> 6;
  const int wr = w >> 1, wc = w & 1;
  const int g = lane >> 4;
  const int lr = lane & 15;

  const int nwg = gridDim.x * gridDim.y;
  const int orig = blockIdx.y * gridDim.x + blockIdx.x;
  const int wg = (orig & 7) * (nwg >> 3) + (orig >> 3);
  const int m0 = (wg / gridDim.x) * 128;
  const int n0 = (wg % gridDim.x) * 128;

  f32x4 acc[4][4] = {};

  const int nkt = K / 64;

  auto stage = [&](int buf, int kt) {
    const int k0 = kt * 64;
#pragma unroll
    for (int i = 0; i < 4; ++i) {
      int c = w * 4 + i;
      int o = c * 1024 + lane * 16;
      int row = o >> 7;
      int ss = ((o >> 4) & 7) ^ (row & 7);
      const char* srcA = (const char*)A + ((size_t)(m0 + row) * K + k0) * 2 + ss * 16;
      gload_lds16(srcA, (char*)(&As[buf][0]) + c * 1024);
      const char* srcB = (const char*)Bm + ((size_t)(n0 + row) * K + k0) * 2 + ss * 16;
      gload_lds16(srcB, (char*)(&Bs[buf][0]) + c * 1024);
    }
  };

  stage(0, 0);
  __syncthreads();
  int cur = 0;
  for (int kt = 0; kt < nkt; ++kt) {
    if (kt + 1 < nkt) stage(cur ^ 1, kt + 1);
#pragma unroll
    for (int ks = 0; ks < 2; ++ks) {
      f16x8 af[4], bf[4];
#pragma unroll
      for (int mf = 0; mf < 4; ++mf) {
        int row = wr * 64 + mf * 16 + lr;
        int slot = (g + 4 * ks) ^ (row & 7);
        af[mf] = *(const f16x8*)((const char*)(&As[cur][0]) + row * 128 + slot * 16);
      }
#pragma unroll
      for (int nf = 0; nf < 4; ++nf) {
        int row = wc * 64 + nf * 16 + lr;
        int slot = (g + 4 * ks) ^ (row & 7);
        bf[nf] = *(const f16x8*)((const char*)(&Bs[cur][0]) + row * 128 + slot * 16);
      }
      __builtin_amdgcn_s_setprio(1);
#pragma unroll
      for (int mf = 0; mf < 4; ++mf)
#pragma unroll
        for (int nf = 0; nf < 4; ++nf)
          acc[mf][nf] = __builtin_amdgcn_mfma_f32_16x16x32_f16(af[mf], bf[nf], acc[mf][nf], 0, 0, 0);
      __builtin_amdgcn_s_setprio(0);
    }
    __syncthreads();
    cur ^= 1;
  }

#pragma unroll
  for (int mf = 0; mf < 4; ++mf)
#pragma unroll
    for (int nf = 0; nf < 4; ++nf)
#pragma unroll
      for (int r = 0; r < 4; ++r) {
        int mm = m0 + wr * 64 + mf * 16 + g * 4 + r;
        int nn = n0 + wc * 64 + nf * 16 + lr;
        C[(size_t)mm * N + nn] = (CT)acc[mf][nf][r];
      }
}

// ---------------- fused RMSNorm (Q heads + K heads) ----------------
__global__ __launch_bounds__(256) void rmsnorm_all(f16* __restrict__ Qb,
                                                   f16* __restrict__ KVb,
                                                   const float* __restrict__ qw,
                                                   const float* __restrict__ kw) {
  int c = blockIdx.x * 4 + (threadIdx.x >> 6);
  int lane = threadIdx.x & 63;
  f16* base; const float* w; float extra;
  if (c < 131072) {                       // Q: 4096 rows x 32 heads
    base = Qb + (size_t)(c >> 5) * 2048 + (c & 31) * 64;
    w = qw; extra = 0.125f;               // fold 1/sqrt(64) attn scale into Q
  } else {                                // K: 4096 rows x 8 heads
    int c2 = c - 131072;
    base = KVb + (size_t)(c2 >> 3) * 1024 + (c2 & 7) * 64;
    w = kw; extra = 1.0f;
  }
  float x = (float)base[lane];
  float ss = x * x;
#pragma unroll
  for (int d = 1; d < 64; d <<= 1) ss += __shfl_xor(ss, d);
  float sc = rsqrtf(ss * (1.0f / 64.0f) + 1e-6f) * extra;
  base[lane] = (f16)(x * sc * w[lane]);
}

// ---------------- V transpose: KV[:,512:] -> VT[b][hk][d][s] ----------------
__global__ __launch_bounds__(256) void vtrans(const f16* __restrict__ KV,
                                              f16* __restrict__ VT) {
  __shared__ f16 tile[64][72];
  int t = threadIdx.x;
  int st = blockIdx.x, hk = blockIdx.y, b = blockIdx.z;
#pragma unroll
  for (int p = 0; p < 2; ++p) {
    int idx = p * 256 + t;
    int s = idx >> 3, c8 = (idx & 7) * 8;
    f16x8 v = *(const f16x8*)(KV + (size_t)(b * SEQ + st * 64 + s) * 1024 + 512 + hk * 64 + c8);
    *(f16x8*)(&tile[s][c8]) = v;
  }
  __syncthreads();
#pragma unroll
  for (int p = 0; p < 2; ++p) {
    int idx = p * 256 + t;
    int d = idx >> 3, s8 = (idx & 7) * 8;
    f16x8 ov;
#pragma unroll
    for (int j = 0; j < 8; ++j) ov[j] = tile[s8 + j][d];
    *(f16x8*)(VT + ((size_t)((b * NKV + hk) * 64) + d) * SEQ + st * 64 + s8) = ov;
  }
}

// ---------------- causal GQA flash attention ----------------
// block = (qt of 64 q-rows, head-pair, b): 8 waves = 2 heads x 4 row-groups.
// The head pair (2y, 2y+1) shares one GQA group -> one K/V staging serves both.
// Fixed-max softmax (RMSNorm bounds s in [-8,8]); dbuf staging, 1 barrier/tile,
// LPT (qt reversed), T5 setprio.
__global__ __launch_bounds__(512) void attn(const f16* __restrict__ Q,
                                            const f16* __restrict__ KV,
                                            const f16* __restrict__ VT,
                                            f16* __restrict__ AO) {
  __shared__ f16 Ks[2][64 * 64];   // [kv][d], slot-swizzled
  __shared__ f16 Vs[2][64 * 64];   // V^T: [d][kv], slot-swizzled
  __shared__ f16 Ps[8][16 * 64];   // per-wave P
  const int t = threadIdx.x, lane = t & 63, w = t >> 6;
  const int g = lane >> 4, lr = lane & 15;
  const int qt = 31 - blockIdx.x;  // longest blocks first (LPT)
  const int h = 2 * blockIdx.y + (w >> 2);
  const int rg = w & 3;
  const int b = blockIdx.z;
  const int hk = h >> 2;
  const int q0 = qt * 64;

  const size_t qrow = (size_t)(b * SEQ + q0 + rg * 16 + lr);
  f16x8 qf[2];
  qf[0] = *(const f16x8*)(Q + qrow * HID + h * 64 + g * 8);
  qf[1] = *(const f16x8*)(Q + qrow * HID + h * 64 + g * 8 + 32);

  f32x4 oacc[4] = {};
  f32x4 psum = {0.f, 0.f, 0.f, 0.f};

  char* Pw = (char*)(&Ps[w][0]);
  const int nkt = qt + 1;

  auto stage = [&](int buf, int kt) {
    int o = w * 1024 + lane * 16;
    int row = o >> 7;
    int ss = ((o >> 4) & 7) ^ (row & 7);
    gload_lds16((const char*)KV + ((size_t)(b * SEQ + kt * 64 + row) * 1024 + hk * 64) * 2 + ss * 16,
                (char*)(&Ks[buf][0]) + w * 1024);
    gload_lds16((const char*)VT + (((size_t)((b * NKV + hk) * 64) + row) * SEQ + kt * 64) * 2 + ss * 16,
                (char*)(&Vs[buf][0]) + w * 1024);
  };

  stage(0, 0);
  __syncthreads();
  int cur = 0;
  for (int kt = 0; kt < nkt; ++kt) {
    if (kt + 1 < nkt) stage(cur ^ 1, kt + 1);

    // S = Q K^T (1/8 scale folded into Q by rmsnorm)
    f32x4 sacc[4] = {};
#pragma unroll
    for (int ks = 0; ks < 2; ++ks) {
      f16x8 kf[4];
#pragma unroll
      for (int nf = 0; nf < 4; ++nf) {
        int row = nf * 16 + lr;
        int slot = (g + 4 * ks) ^ (row & 7);
        kf[nf] = *(const f16x8*)((const char*)(&Ks[cur][0]) + row * 128 + slot * 16);
      }
      __builtin_amdgcn_s_setprio(1);
#pragma unroll
      for (int nf = 0; nf < 4; ++nf)
        sacc[nf] = __builtin_amdgcn_mfma_f32_16x16x32_f16(qf[ks], kf[nf], sacc[nf], 0, 0, 0);
      __builtin_amdgcn_s_setprio(0);
    }

    if (kt == qt) {  // diagonal tile: causal mask
#pragma unroll
      for (int nf = 0; nf < 4; ++nf) {
        int kv = kt * 64 + nf * 16 + lr;
#pragma unroll
        for (int r = 0; r < 4; ++r) {
          int qq = q0 + rg * 16 + g * 4 + r;
          if (kv > qq) sacc[nf][r] = -1e30f;
        }
      }
    }

    // P = exp(s); per-lane partial row-sum; store P^T fragment to LDS
#pragma unroll
    for (int nf = 0; nf < 4; ++nf)
#pragma unroll
      for (int r = 0; r < 4; ++r) {
        float p = __expf(sacc[nf][r]);
        psum[r] += p;
        int row = g * 4 + r, col = nf * 16 + lr;
        *(f16*)(Pw + row * 128 + (((col >> 3) ^ (row & 7)) * 16) + (col & 7) * 2) = (f16)p;
      }

    asm volatile("s_waitcnt lgkmcnt(0)" ::: "memory");

    // O += P V
#pragma unroll
    for (int ks = 0; ks < 2; ++ks) {
      f16x8 pf = *(const f16x8*)(Pw + lr * 128 + (((g + 4 * ks) ^ (lr & 7)) * 16));
      f16x8 vf[4];
#pragma unroll
      for (int df = 0; df < 4; ++df) {
        int row = df * 16 + lr;
        int slot = (g + 4 * ks) ^ (row & 7);
        vf[df] = *(const f16x8*)((const char*)(&Vs[cur][0]) + row * 128 + slot * 16);
      }
      __builtin_amdgcn_s_setprio(1);
#pragma unroll
      for (int df = 0; df < 4; ++df)
        oacc[df] = __builtin_amdgcn_mfma_f32_16x16x32_f16(pf, vf[df], oacc[df], 0, 0, 0);
      __builtin_amdgcn_s_setprio(0);
    }

    __syncthreads();
    cur ^= 1;
  }

  // final row-sum reduce across the 16-lane lr group
#pragma unroll
  for (int d = 1; d < 16; d <<= 1)
#pragma unroll
    for (int r = 0; r < 4; ++r) psum[r] += __shfl_xor(psum[r], d);

#pragma unroll
  for (int df = 0; df < 4; ++df)
#pragma unroll
    for (int r = 0; r < 4; ++r) {
      size_t rowg = (size_t)(b * SEQ + q0 + rg * 16 + g * 4 + r);
      AO[rowg * HID + h * 64 + df * 16 + lr] = (f16)(oacc[df][r] / psum[r]);
    }
}

// ---------------- launch ----------------
extern "C" void kernel_launch(void* const* d_in, const int* in_sizes, int n_in,
                              void* d_out, int out_size, void* d_ws, size_t ws_size,
                              hipStream_t stream) {
  const float* X  = (const float*)d_in[0];
  const float* Wq = (const float*)d_in[1];
  const float* Wk = (const float*)d_in[2];
  const float* Wv = (const float*)d_in[3];
  const float* Wo = (const float*)d_in[4];
  const float* qw = (const float*)d_in[5];
  const float* kw = (const float*)d_in[6];

  char* ws = (char*)d_ws;
  f16* Xb   = (f16*)(ws + 0);           // 4096 x 2048
  f16* Wqb  = (f16*)(ws + 16777216);    // 2048 x 2048
  f16* Wkvb = (f16*)(ws + 25165824);    // 1024 x 2048 (Wk rows then Wv rows)
  f16* Wob  = (f16*)(ws + 29360128);    // 2048 x 2048
  f16* Qb   = (f16*)(ws + 37748736);    // 4096 x 2048
  f16* KVb  = (f16*)(ws + 54525952);    // 4096 x 1024 (K cols 0..511, V cols 512..1023)
  f16* VTb  = (f16*)(ws + 62914560);    // [2][8][64][2048]
  f16* AOb  = (f16*)(ws + 67108864);    // 4096 x 2048
  float* OUT = (float*)d_out;

  cvt_all<<<18432, 256, 0, stream>>>(X, Wq, Wk, Wv, Wo,
                                     Xb, Wqb, Wkvb, Wkvb + 512 * 2048, Wob);

  gemm_bt<f16><<<dim3(16, 32), 256, 0, stream>>>(Xb, Wqb, Qb, 4096, 2048, 2048);
  gemm_bt<f16><<<dim3(8, 32), 256, 0, stream>>>(Xb, Wkvb, KVb, 4096, 1024, 2048);

  rmsnorm_all<<<40960, 256, 0, stream>>>(Qb, KVb, qw, kw);

  vtrans<<<dim3(32, 8, 2), 256, 0, stream>>>(KVb, VTb);
  attn<<<dim3(32, 16, 2), 512, 0, stream>>>(Qb, KVb, VTb, AOb);

  gemm_bt<float><<<dim3(16, 32), 256, 0, stream>>>(AOb, Wob, OUT, 4096, 2048, 2048);
}

// Round 6
// 213.645 us; speedup vs baseline: 1.9115x; 1.1867x over previous
//
#include <hip/hip_runtime.h>

typedef _Float16 f16;
typedef _Float16 f16x8 __attribute__((ext_vector_type(8)));
typedef _Float16 f16x4 __attribute__((ext_vector_type(4)));
typedef float f32x4 __attribute__((ext_vector_type(4)));

#define HID 2048
#define NH 32
#define NKV 8
#define HD 64
#define SEQ 2048
#define NB 2

__device__ __forceinline__ void gload_lds16(const void* g, void* l) {
  __builtin_amdgcn_global_load_lds((const __attribute__((address_space(1))) void*)g,
                                   (__attribute__((address_space(3))) void*)l, 16, 0, 0);
}

__device__ __forceinline__ uint cvt_pk_f16(float a, float b) {
  auto v = __builtin_amdgcn_cvt_pkrtz(a, b);   // __fp16 ext_vector(2)
  uint u;
  __builtin_memcpy(&u, &v, 4);
  return u;
}

// ---------------- fused f32 -> f16 convert of all 5 tensors ----------------
__global__ __launch_bounds__(256) void cvt_all(const float* __restrict__ X,
                                               const float* __restrict__ Wq,
                                               const float* __restrict__ Wk,
                                               const float* __restrict__ Wv,
                                               const float* __restrict__ Wo,
                                               f16* __restrict__ Xb, f16* __restrict__ Wqb,
                                               f16* __restrict__ Wkb, f16* __restrict__ Wvb,
                                               f16* __restrict__ Wob) {
  long i = (long)blockIdx.x * 256 + threadIdx.x;
  const float* s; f16* d; long o;
  if (i < 2097152)      { s = X;  d = Xb;  o = i; }
  else if (i < 3145728) { s = Wq; d = Wqb; o = i - 2097152; }
  else if (i < 3407872) { s = Wk; d = Wkb; o = i - 3145728; }
  else if (i < 3670016) { s = Wv; d = Wvb; o = i - 3407872; }
  else                  { s = Wo; d = Wob; o = i - 3670016; }
  float4 v = ((const float4*)s)[o];
  f16x4 ov = { (f16)v.x, (f16)v.y, (f16)v.z, (f16)v.w };
  ((f16x4*)d)[o] = ov;
}

// ---------------- GEMM: C[M,N] = A[M,K] * B[N,K]^T ----------------
// 128x128 tile, BK=64, 4 waves (2x2 of 64x64), 16x16x32 f16 MFMA.
// LDS dbuf, global_load_lds w/ pre-swizzled source, T1 XCD swizzle, T5 setprio.
template <typename CT>
__global__ __launch_bounds__(256) void gemm_bt(const f16* __restrict__ A,
                                               const f16* __restrict__ Bm,
                                               CT* __restrict__ C,
                                               int M, int N, int K) {
  __shared__ f16 As[2][128 * 64];
  __shared__ f16 Bs[2][128 * 64];
  const int t = threadIdx.x;
  const int lane = t & 63;
  const int w = t >> 6;
  const int wr = w >> 1, wc = w & 1;
  const int g = lane >> 4;
  const int lr = lane & 15;

  const int nwg = gridDim.x * gridDim.y;
  const int orig = blockIdx.y * gridDim.x + blockIdx.x;
  const int wg = (orig & 7) * (nwg >> 3) + (orig >> 3);
  const int m0 = (wg / gridDim.x) * 128;
  const int n0 = (wg % gridDim.x) * 128;

  f32x4 acc[4][4] = {};

  const int nkt = K / 64;

  auto stage = [&](int buf, int kt) {
    const int k0 = kt * 64;
#pragma unroll
    for (int i = 0; i < 4; ++i) {
      int c = w * 4 + i;
      int o = c * 1024 + lane * 16;
      int row = o >> 7;
      int ss = ((o >> 4) & 7) ^ (row & 7);
      const char* srcA = (const char*)A + ((size_t)(m0 + row) * K + k0) * 2 + ss * 16;
      gload_lds16(srcA, (char*)(&As[buf][0]) + c * 1024);
      const char* srcB = (const char*)Bm + ((size_t)(n0 + row) * K + k0) * 2 + ss * 16;
      gload_lds16(srcB, (char*)(&Bs[buf][0]) + c * 1024);
    }
  };

  stage(0, 0);
  __syncthreads();
  int cur = 0;
  for (int kt = 0; kt < nkt; ++kt) {
    if (kt + 1 < nkt) stage(cur ^ 1, kt + 1);
#pragma unroll
    for (int ks = 0; ks < 2; ++ks) {
      f16x8 af[4], bf[4];
#pragma unroll
      for (int mf = 0; mf < 4; ++mf) {
        int row = wr * 64 + mf * 16 + lr;
        int slot = (g + 4 * ks) ^ (row & 7);
        af[mf] = *(const f16x8*)((const char*)(&As[cur][0]) + row * 128 + slot * 16);
      }
#pragma unroll
      for (int nf = 0; nf < 4; ++nf) {
        int row = wc * 64 + nf * 16 + lr;
        int slot = (g + 4 * ks) ^ (row & 7);
        bf[nf] = *(const f16x8*)((const char*)(&Bs[cur][0]) + row * 128 + slot * 16);
      }
      __builtin_amdgcn_s_setprio(1);
#pragma unroll
      for (int mf = 0; mf < 4; ++mf)
#pragma unroll
        for (int nf = 0; nf < 4; ++nf)
          acc[mf][nf] = __builtin_amdgcn_mfma_f32_16x16x32_f16(af[mf], bf[nf], acc[mf][nf], 0, 0, 0);
      __builtin_amdgcn_s_setprio(0);
    }
    __syncthreads();
    cur ^= 1;
  }

#pragma unroll
  for (int mf = 0; mf < 4; ++mf)
#pragma unroll
    for (int nf = 0; nf < 4; ++nf)
#pragma unroll
      for (int r = 0; r < 4; ++r) {
        int mm = m0 + wr * 64 + mf * 16 + g * 4 + r;
        int nn = n0 + wc * 64 + nf * 16 + lr;
        C[(size_t)mm * N + nn] = (CT)acc[mf][nf][r];
      }
}

// ---------------- fused RMSNorm (Q heads + K heads) ----------------
__global__ __launch_bounds__(256) void rmsnorm_all(f16* __restrict__ Qb,
                                                   f16* __restrict__ KVb,
                                                   const float* __restrict__ qw,
                                                   const float* __restrict__ kw) {
  int c = blockIdx.x * 4 + (threadIdx.x >> 6);
  int lane = threadIdx.x & 63;
  f16* base; const float* w; float extra;
  if (c < 131072) {                       // Q: 4096 rows x 32 heads
    base = Qb + (size_t)(c >> 5) * 2048 + (c & 31) * 64;
    w = qw; extra = 0.125f;               // fold 1/sqrt(64) attn scale into Q
  } else {                                // K: 4096 rows x 8 heads
    int c2 = c - 131072;
    base = KVb + (size_t)(c2 >> 3) * 1024 + (c2 & 7) * 64;
    w = kw; extra = 1.0f;
  }
  float x = (float)base[lane];
  float ss = x * x;
#pragma unroll
  for (int d = 1; d < 64; d <<= 1) ss += __shfl_xor(ss, d);
  float sc = rsqrtf(ss * (1.0f / 64.0f) + 1e-6f) * extra;
  base[lane] = (f16)(x * sc * w[lane]);
}

// ---------------- V transpose: KV[:,512:] -> VT[b][hk][d][s] ----------------
__global__ __launch_bounds__(256) void vtrans(const f16* __restrict__ KV,
                                              f16* __restrict__ VT) {
  __shared__ f16 tile[64][72];
  int t = threadIdx.x;
  int st = blockIdx.x, hk = blockIdx.y, b = blockIdx.z;
#pragma unroll
  for (int p = 0; p < 2; ++p) {
    int idx = p * 256 + t;
    int s = idx >> 3, c8 = (idx & 7) * 8;
    f16x8 v = *(const f16x8*)(KV + (size_t)(b * SEQ + st * 64 + s) * 1024 + 512 + hk * 64 + c8);
    *(f16x8*)(&tile[s][c8]) = v;
  }
  __syncthreads();
#pragma unroll
  for (int p = 0; p < 2; ++p) {
    int idx = p * 256 + t;
    int d = idx >> 3, s8 = (idx & 7) * 8;
    f16x8 ov;
#pragma unroll
    for (int j = 0; j < 8; ++j) ov[j] = tile[s8 + j][d];
    *(f16x8*)(VT + ((size_t)((b * NKV + hk) * 64) + d) * SEQ + st * 64 + s8) = ov;
  }
}

// ---------------- causal GQA flash attention ----------------
// block = (col = hpair*2+b on x, qt-rank on y): 8 waves = 2 heads x 4 row-groups.
// Swapped QK^T: sacc = mfma(K, Q) -> lane holds P[q=lr][k], so P stays in
// registers (no LDS round-trip). PV uses a matching k-permutation:
// hardware-k (g,j) -> logical k = 32m + 16*(j>>2) + 4g + (j&3) on BOTH operands.
// Fixed-max softmax (RMSNorm bounds s in [-8,8] -> exp(s) fits f16).
// 3-buffer staging with counted vmcnt + raw barrier (loads stay in flight
// across barriers); global LPT (heaviest qt dispatched first).
__global__ __launch_bounds__(512) void attn(const f16* __restrict__ Q,
                                            const f16* __restrict__ KV,
                                            const f16* __restrict__ VT,
                                            f16* __restrict__ AO) {
  __shared__ f16 Ks[3][64 * 64];   // [kv][d], slot-swizzled
  __shared__ f16 Vs[3][64 * 64];   // V^T: [d][kv], slot-swizzled
  const int t = threadIdx.x, lane = t & 63, w = t >> 6;
  const int g = lane >> 4, lr = lane & 15;
  const int col = blockIdx.x;            // hpair*2 + b
  const int qt = 31 - blockIdx.y;        // heaviest first (true global LPT)
  const int b = col & 1;
  const int h = 2 * (col >> 1) + (w >> 2);
  const int rg = w & 3;
  const int hk = h >> 2;
  const int q0 = qt * 64;

  const size_t qrow = (size_t)(b * SEQ + q0 + rg * 16 + lr);
  f16x8 qf[2];
  qf[0] = *(const f16x8*)(Q + qrow * HID + h * 64 + g * 8);
  qf[1] = *(const f16x8*)(Q + qrow * HID + h * 64 + g * 8 + 32);

  f32x4 oacc[4] = {};
  float psum = 0.0f;

  const int nkt = qt + 1;

  auto stage = [&](int buf, int kt2) {
    int o = w * 1024 + lane * 16;
    int row = o >> 7;
    int ss = ((o >> 4) & 7) ^ (row & 7);
    gload_lds16((const char*)KV + ((size_t)(b * SEQ + kt2 * 64 + row) * 1024 + hk * 64) * 2 + ss * 16,
                (char*)(&Ks[buf][0]) + w * 1024);
    gload_lds16((const char*)VT + (((size_t)((b * NKV + hk) * 64) + row) * SEQ + kt2 * 64) * 2 + ss * 16,
                (char*)(&Vs[buf][0]) + w * 1024);
  };

  stage(0, 0);
  if (nkt > 1) stage(1, 1);
  int cur = 0;
  for (int kt = 0; kt < nkt; ++kt) {
    // tile-kt loads guaranteed done; newer (kt+1) loads stay in flight
    if (kt + 1 < nkt) asm volatile("s_waitcnt vmcnt(2)" ::: "memory");
    else              asm volatile("s_waitcnt vmcnt(0)" ::: "memory");
    __builtin_amdgcn_s_barrier();
    asm volatile("" ::: "memory");

    if (kt + 2 < nkt) {
      int nb = cur + 2; if (nb >= 3) nb -= 3;
      stage(nb, kt + 2);
    }

    // S^T = K Q^T : lane holds S[q=lr][k = nf*16 + g*4 + r]
    f32x4 sacc[4] = {};
#pragma unroll
    for (int ks = 0; ks < 2; ++ks) {
      __builtin_amdgcn_s_setprio(1);
#pragma unroll
      for (int nf = 0; nf < 4; ++nf) {
        int row = nf * 16 + lr;
        int slot = (g + 4 * ks) ^ (row & 7);
        f16x8 kf = *(const f16x8*)((const char*)(&Ks[cur][0]) + row * 128 + slot * 16);
        sacc[nf] = __builtin_amdgcn_mfma_f32_16x16x32_f16(kf, qf[ks], sacc[nf], 0, 0, 0);
      }
      __builtin_amdgcn_s_setprio(0);
    }

    if (kt == qt) {  // diagonal tile: causal mask (q = q0+rg*16+lr, lane-const)
      int qq = q0 + rg * 16 + lr;
#pragma unroll
      for (int nf = 0; nf < 4; ++nf) {
        int kvb = kt * 64 + nf * 16 + g * 4;
#pragma unroll
        for (int r = 0; r < 4; ++r)
          if (kvb + r > qq) sacc[nf][r] = -1e30f;
      }
    }

    // P = exp(S) packed to f16 in-register; per-lane partial row-sum
    uint pk[8];
#pragma unroll
    for (int nf = 0; nf < 4; ++nf) {
      float p0 = __expf(sacc[nf][0]);
      float p1 = __expf(sacc[nf][1]);
      float p2 = __expf(sacc[nf][2]);
      float p3 = __expf(sacc[nf][3]);
      psum += (p0 + p1) + (p2 + p3);
      pk[2 * nf]     = cvt_pk_f16(p0, p1);
      pk[2 * nf + 1] = cvt_pk_f16(p2, p3);
    }

    // O += P V with permuted k-mapping; V fragments as 2x ds_read_b64
#pragma unroll
    for (int m = 0; m < 2; ++m) {
      union { uint u[4]; f16x8 v; } pu;
      pu.u[0] = pk[4 * m];     pu.u[1] = pk[4 * m + 1];
      pu.u[2] = pk[4 * m + 2]; pu.u[3] = pk[4 * m + 3];
      const char* Vb = (const char*)(&Vs[cur][0]);
      __builtin_amdgcn_s_setprio(1);
#pragma unroll
      for (int df = 0; df < 4; ++df) {
        int row = df * 16 + lr;
        int swz = row & 7;
        const char* rp = Vb + row * 128 + (g & 1) * 8;
        f16x4 lo = *(const f16x4*)(rp + (((4 * m + (g >> 1)) ^ swz) * 16));
        f16x4 hi = *(const f16x4*)(rp + (((4 * m + 2 + (g >> 1)) ^ swz) * 16));
        f16x8 vf = { lo[0], lo[1], lo[2], lo[3], hi[0], hi[1], hi[2], hi[3] };
        oacc[df] = __builtin_amdgcn_mfma_f32_16x16x32_f16(pu.v, vf, oacc[df], 0, 0, 0);
      }
      __builtin_amdgcn_s_setprio(0);
    }

    cur = (cur == 2) ? 0 : cur + 1;
  }

  // full row-sum for q=lr lives spread over the 4 g-lanes: xor-reduce, then
  // fetch the sum for this lane's OUTPUT rows (q_local = g*4+r)
  psum += __shfl_xor(psum, 16);
  psum += __shfl_xor(psum, 32);
  float pdiv[4];
#pragma unroll
  for (int r = 0; r < 4; ++r) pdiv[r] = __shfl(psum, g * 4 + r);

#pragma unroll
  for (int df = 0; df < 4; ++df)
#pragma unroll
    for (int r = 0; r < 4; ++r) {
      size_t rowg = (size_t)(b * SEQ + q0 + rg * 16 + g * 4 + r);
      AO[rowg * HID + h * 64 + df * 16 + lr] = (f16)(oacc[df][r] / pdiv[r]);
    }
}

// ---------------- launch ----------------
extern "C" void kernel_launch(void* const* d_in, const int* in_sizes, int n_in,
                              void* d_out, int out_size, void* d_ws, size_t ws_size,
                              hipStream_t stream) {
  const float* X  = (const float*)d_in[0];
  const float* Wq = (const float*)d_in[1];
  const float* Wk = (const float*)d_in[2];
  const float* Wv = (const float*)d_in[3];
  const float* Wo = (const float*)d_in[4];
  const float* qw = (const float*)d_in[5];
  const float* kw = (const float*)d_in[6];

  char* ws = (char*)d_ws;
  f16* Xb   = (f16*)(ws + 0);           // 4096 x 2048
  f16* Wqb  = (f16*)(ws + 16777216);    // 2048 x 2048
  f16* Wkvb = (f16*)(ws + 25165824);    // 1024 x 2048 (Wk rows then Wv rows)
  f16* Wob  = (f16*)(ws + 29360128);    // 2048 x 2048
  f16* Qb   = (f16*)(ws + 37748736);    // 4096 x 2048
  f16* KVb  = (f16*)(ws + 54525952);    // 4096 x 1024 (K cols 0..511, V cols 512..1023)
  f16* VTb  = (f16*)(ws + 62914560);    // [2][8][64][2048]
  f16* AOb  = (f16*)(ws + 67108864);    // 4096 x 2048
  float* OUT = (float*)d_out;

  cvt_all<<<18432, 256, 0, stream>>>(X, Wq, Wk, Wv, Wo,
                                     Xb, Wqb, Wkvb, Wkvb + 512 * 2048, Wob);

  gemm_bt<f16><<<dim3(16, 32), 256, 0, stream>>>(Xb, Wqb, Qb, 4096, 2048, 2048);
  gemm_bt<f16><<<dim3(8, 32), 256, 0, stream>>>(Xb, Wkvb, KVb, 4096, 1024, 2048);

  rmsnorm_all<<<40960, 256, 0, stream>>>(Qb, KVb, qw, kw);

  vtrans<<<dim3(32, 8, 2), 256, 0, stream>>>(KVb, VTb);
  attn<<<dim3(32, 32, 1), 512, 0, stream>>>(Qb, KVb, VTb, AOb);

  gemm_bt<float><<<dim3(16, 32), 256, 0, stream>>>(AOb, Wob, OUT, 4096, 2048, 2048);
}

// Round 7
// 192.212 us; speedup vs baseline: 2.1247x; 1.1115x over previous
//
#include <hip/hip_runtime.h>

typedef _Float16 f16;
typedef _Float16 f16x8 __attribute__((ext_vector_type(8)));
typedef _Float16 f16x4 __attribute__((ext_vector_type(4)));
typedef __fp16 fp16x2 __attribute__((ext_vector_type(2)));
typedef float f32x4 __attribute__((ext_vector_type(4)));

#define HID 2048
#define NH 32
#define NKV 8
#define HD 64
#define SEQ 2048
#define NB 2

__device__ __forceinline__ void gload_lds16(const void* g, void* l) {
  __builtin_amdgcn_global_load_lds((const __attribute__((address_space(1))) void*)g,
                                   (__attribute__((address_space(3))) void*)l, 16, 0, 0);
}

__device__ __forceinline__ uint cvt_pk_f16(float a, float b) {
  auto v = __builtin_amdgcn_cvt_pkrtz(a, b);   // __fp16 ext_vector(2)
  uint u;
  __builtin_memcpy(&u, &v, 4);
  return u;
}

__device__ __forceinline__ float fdot2_ones(uint pk, float acc) {
  fp16x2 a;
  __builtin_memcpy(&a, &pk, 4);
  fp16x2 ones = {(__fp16)1.0f, (__fp16)1.0f};
  return __builtin_amdgcn_fdot2(a, ones, acc, false);
}

// ---------------- fused f32 -> f16 convert of all 5 tensors ----------------
__global__ __launch_bounds__(256) void cvt_all(const float* __restrict__ X,
                                               const float* __restrict__ Wq,
                                               const float* __restrict__ Wk,
                                               const float* __restrict__ Wv,
                                               const float* __restrict__ Wo,
                                               f16* __restrict__ Xb, f16* __restrict__ Wqb,
                                               f16* __restrict__ Wkb, f16* __restrict__ Wvb,
                                               f16* __restrict__ Wob) {
  long i = (long)blockIdx.x * 256 + threadIdx.x;
  const float* s; f16* d; long o;
  if (i < 2097152)      { s = X;  d = Xb;  o = i; }
  else if (i < 3145728) { s = Wq; d = Wqb; o = i - 2097152; }
  else if (i < 3407872) { s = Wk; d = Wkb; o = i - 3145728; }
  else if (i < 3670016) { s = Wv; d = Wvb; o = i - 3407872; }
  else                  { s = Wo; d = Wob; o = i - 3670016; }
  float4 v = ((const float4*)s)[o];
  f16x4 ov = { (f16)v.x, (f16)v.y, (f16)v.z, (f16)v.w };
  ((f16x4*)d)[o] = ov;
}

// ---------------- GEMM: C[M,N] = A[M,K] * B[N,K]^T ----------------
// 128x128 tile, BK=64, 4 waves, 16x16x32 f16 MFMA. Counted-vmcnt pipeline:
// prologue stages tiles 0,1; per iter: vmcnt(8)+barrier (next tile's loads
// stay in flight) -> read all fragments -> lgkm(0)+sched_barrier+barrier ->
// stage(kt+2) -> MFMA cluster. T1 XCD swizzle, T2 slot swizzle, T5 setprio.
// Split epilogue: cols < n_split go to C0 (ldc0), rest to C1 (ldc1).
template <typename CT>
__global__ __launch_bounds__(256) void gemm_bt(const f16* __restrict__ A,
                                               const f16* __restrict__ Bm,
                                               CT* __restrict__ C0, CT* __restrict__ C1,
                                               int M, int N, int K,
                                               int n_split, int ldc0, int ldc1) {
  __shared__ f16 As[2][128 * 64];
  __shared__ f16 Bs[2][128 * 64];
  const int t = threadIdx.x;
  const int lane = t & 63;
  const int w = t >> 6;
  const int wr = w >> 1, wc = w & 1;
  const int g = lane >> 4;
  const int lr = lane & 15;

  const int nwg = gridDim.x * gridDim.y;
  const int orig = blockIdx.y * gridDim.x + blockIdx.x;
  const int wg = (orig & 7) * (nwg >> 3) + (orig >> 3);
  const int m0 = (wg / gridDim.x) * 128;
  const int n0 = (wg % gridDim.x) * 128;

  f32x4 acc[4][4] = {};

  const int nkt = K / 64;

  auto stage = [&](int buf, int kt) {
    const int k0 = kt * 64;
#pragma unroll
    for (int i = 0; i < 4; ++i) {
      int c = w * 4 + i;
      int o = c * 1024 + lane * 16;
      int row = o >> 7;
      int ss = ((o >> 4) & 7) ^ (row & 7);
      const char* srcA = (const char*)A + ((size_t)(m0 + row) * K + k0) * 2 + ss * 16;
      gload_lds16(srcA, (char*)(&As[buf][0]) + c * 1024);
      const char* srcB = (const char*)Bm + ((size_t)(n0 + row) * K + k0) * 2 + ss * 16;
      gload_lds16(srcB, (char*)(&Bs[buf][0]) + c * 1024);
    }
  };

  stage(0, 0);
  if (nkt > 1) stage(1, 1);
  for (int kt = 0; kt < nkt; ++kt) {
    const int cur = kt & 1;
    if (kt + 1 < nkt) asm volatile("s_waitcnt vmcnt(8)" ::: "memory");
    else              asm volatile("s_waitcnt vmcnt(0)" ::: "memory");
    __builtin_amdgcn_s_barrier();
    __builtin_amdgcn_sched_barrier(0);

    f16x8 af[2][4], bf[2][4];
#pragma unroll
    for (int ks = 0; ks < 2; ++ks)
#pragma unroll
      for (int mf = 0; mf < 4; ++mf) {
        int row = wr * 64 + mf * 16 + lr;
        int slot = (g + 4 * ks) ^ (row & 7);
        af[ks][mf] = *(const f16x8*)((const char*)(&As[cur][0]) + row * 128 + slot * 16);
      }
#pragma unroll
    for (int ks = 0; ks < 2; ++ks)
#pragma unroll
      for (int nf = 0; nf < 4; ++nf) {
        int row = wc * 64 + nf * 16 + lr;
        int slot = (g + 4 * ks) ^ (row & 7);
        bf[ks][nf] = *(const f16x8*)((const char*)(&Bs[cur][0]) + row * 128 + slot * 16);
      }
    asm volatile("s_waitcnt lgkmcnt(0)" ::: "memory");
    __builtin_amdgcn_sched_barrier(0);
    __builtin_amdgcn_s_barrier();

    if (kt + 2 < nkt) stage(cur, kt + 2);

    __builtin_amdgcn_s_setprio(1);
#pragma unroll
    for (int ks = 0; ks < 2; ++ks)
#pragma unroll
      for (int mf = 0; mf < 4; ++mf)
#pragma unroll
        for (int nf = 0; nf < 4; ++nf)
          acc[mf][nf] = __builtin_amdgcn_mfma_f32_16x16x32_f16(af[ks][mf], bf[ks][nf], acc[mf][nf], 0, 0, 0);
    __builtin_amdgcn_s_setprio(0);
  }

  CT* Cp; int ldc, nb;
  if (n0 < n_split) { Cp = C0; ldc = ldc0; nb = n0; }
  else              { Cp = C1; ldc = ldc1; nb = n0 - n_split; }
#pragma unroll
  for (int mf = 0; mf < 4; ++mf)
#pragma unroll
    for (int nf = 0; nf < 4; ++nf)
#pragma unroll
      for (int r = 0; r < 4; ++r) {
        int mm = m0 + wr * 64 + mf * 16 + g * 4 + r;
        int nn = nb + wc * 64 + nf * 16 + lr;
        Cp[(size_t)mm * ldc + nn] = (CT)acc[mf][nf][r];
      }
}

// ---------------- fused RMSNorm (Q heads + K heads) ----------------
__global__ __launch_bounds__(256) void rmsnorm_all(f16* __restrict__ Qb,
                                                   f16* __restrict__ KVb,
                                                   const float* __restrict__ qw,
                                                   const float* __restrict__ kw) {
  int c = blockIdx.x * 4 + (threadIdx.x >> 6);
  int lane = threadIdx.x & 63;
  f16* base; const float* w; float extra;
  if (c < 131072) {                       // Q: 4096 rows x 32 heads
    base = Qb + (size_t)(c >> 5) * 2048 + (c & 31) * 64;
    w = qw; extra = 0.125f;               // fold 1/sqrt(64) attn scale into Q
  } else {                                // K: 4096 rows x 8 heads
    int c2 = c - 131072;
    base = KVb + (size_t)(c2 >> 3) * 1024 + (c2 & 7) * 64;
    w = kw; extra = 1.0f;
  }
  float x = (float)base[lane];
  float ss = x * x;
#pragma unroll
  for (int d = 1; d < 64; d <<= 1) ss += __shfl_xor(ss, d);
  float sc = rsqrtf(ss * (1.0f / 64.0f) + 1e-6f) * extra;
  base[lane] = (f16)(x * sc * w[lane]);
}

// ---------------- V transpose: KV[:,512:] -> VT[b][hk][d][s] ----------------
__global__ __launch_bounds__(256) void vtrans(const f16* __restrict__ KV,
                                              f16* __restrict__ VT) {
  __shared__ f16 tile[64][72];
  int t = threadIdx.x;
  int st = blockIdx.x, hk = blockIdx.y, b = blockIdx.z;
#pragma unroll
  for (int p = 0; p < 2; ++p) {
    int idx = p * 256 + t;
    int s = idx >> 3, c8 = (idx & 7) * 8;
    f16x8 v = *(const f16x8*)(KV + (size_t)(b * SEQ + st * 64 + s) * 1024 + 512 + hk * 64 + c8);
    *(f16x8*)(&tile[s][c8]) = v;
  }
  __syncthreads();
#pragma unroll
  for (int p = 0; p < 2; ++p) {
    int idx = p * 256 + t;
    int d = idx >> 3, s8 = (idx & 7) * 8;
    f16x8 ov;
#pragma unroll
    for (int j = 0; j < 8; ++j) ov[j] = tile[s8 + j][d];
    *(f16x8*)(VT + ((size_t)((b * NKV + hk) * 64) + d) * SEQ + st * 64 + s8) = ov;
  }
}

// ---------------- causal GQA flash attention ----------------
// block = (col = hpair*2+b on x, qt-rank on y): 8 waves = 2 heads x 4 row-groups.
// Swapped QK^T keeps P in registers; PV k-permutation matched on both operands.
// Fixed-max softmax; 3-buffer staging with counted vmcnt + raw barrier;
// global LPT; psum via v_dot2_f32_f16 on packed P; hoisted LDS offsets.
__global__ __launch_bounds__(512) void attn(const f16* __restrict__ Q,
                                            const f16* __restrict__ KV,
                                            const f16* __restrict__ VT,
                                            f16* __restrict__ AO) {
  __shared__ f16 Ks[3][64 * 64];   // [kv][d], slot-swizzled
  __shared__ f16 Vs[3][64 * 64];   // V^T: [d][kv], slot-swizzled
  const int t = threadIdx.x, lane = t & 63, w = t >> 6;
  const int g = lane >> 4, lr = lane & 15;
  const int col = blockIdx.x;            // hpair*2 + b
  const int qt = 31 - blockIdx.y;        // heaviest first (true global LPT)
  const int b = col & 1;
  const int h = 2 * (col >> 1) + (w >> 2);
  const int rg = w & 3;
  const int hk = h >> 2;
  const int q0 = qt * 64;

  const size_t qrow = (size_t)(b * SEQ + q0 + rg * 16 + lr);
  f16x8 qf[2];
  qf[0] = *(const f16x8*)(Q + qrow * HID + h * 64 + g * 8);
  qf[1] = *(const f16x8*)(Q + qrow * HID + h * 64 + g * 8 + 32);

  // hoisted LDS byte offsets (loop-invariant across kv tiles)
  int koff[2][4], vlo[2][4], vhi[2][4];
#pragma unroll
  for (int ks = 0; ks < 2; ++ks)
#pragma unroll
    for (int nf = 0; nf < 4; ++nf) {
      int row = nf * 16 + lr;
      koff[ks][nf] = row * 128 + (((g + 4 * ks) ^ (row & 7)) * 16);
    }
#pragma unroll
  for (int m = 0; m < 2; ++m)
#pragma unroll
    for (int df = 0; df < 4; ++df) {
      int row = df * 16 + lr;
      int base = row * 128 + (g & 1) * 8;
      vlo[m][df] = base + (((4 * m + (g >> 1)) ^ (row & 7)) * 16);
      vhi[m][df] = base + (((4 * m + 2 + (g >> 1)) ^ (row & 7)) * 16);
    }

  f32x4 oacc[4] = {};
  float psum0 = 0.0f, psum1 = 0.0f;

  const int nkt = qt + 1;

  auto stage = [&](int buf, int kt2) {
    int o = w * 1024 + lane * 16;
    int row = o >> 7;
    int ss = ((o >> 4) & 7) ^ (row & 7);
    gload_lds16((const char*)KV + ((size_t)(b * SEQ + kt2 * 64 + row) * 1024 + hk * 64) * 2 + ss * 16,
                (char*)(&Ks[buf][0]) + w * 1024);
    gload_lds16((const char*)VT + (((size_t)((b * NKV + hk) * 64) + row) * SEQ + kt2 * 64) * 2 + ss * 16,
                (char*)(&Vs[buf][0]) + w * 1024);
  };

  stage(0, 0);
  if (nkt > 1) stage(1, 1);
  int cur = 0;
  for (int kt = 0; kt < nkt; ++kt) {
    // tile-kt loads guaranteed done; newer (kt+1) loads stay in flight
    if (kt + 1 < nkt) asm volatile("s_waitcnt vmcnt(2)" ::: "memory");
    else              asm volatile("s_waitcnt vmcnt(0)" ::: "memory");
    __builtin_amdgcn_s_barrier();
    asm volatile("" ::: "memory");

    if (kt + 2 < nkt) {
      int nb = cur + 2; if (nb >= 3) nb -= 3;
      stage(nb, kt + 2);
    }

    const char* Kb = (const char*)(&Ks[cur][0]);
    const char* Vb = (const char*)(&Vs[cur][0]);

    // S^T = K Q^T : lane holds S[q=lr][k = nf*16 + g*4 + r]
    f32x4 sacc[4] = {};
#pragma unroll
    for (int ks = 0; ks < 2; ++ks) {
      __builtin_amdgcn_s_setprio(1);
#pragma unroll
      for (int nf = 0; nf < 4; ++nf) {
        f16x8 kf = *(const f16x8*)(Kb + koff[ks][nf]);
        sacc[nf] = __builtin_amdgcn_mfma_f32_16x16x32_f16(kf, qf[ks], sacc[nf], 0, 0, 0);
      }
      __builtin_amdgcn_s_setprio(0);
    }

    if (kt == qt) {  // diagonal tile: causal mask (q = q0+rg*16+lr, lane-const)
      int qq = q0 + rg * 16 + lr;
#pragma unroll
      for (int nf = 0; nf < 4; ++nf) {
        int kvb = kt * 64 + nf * 16 + g * 4;
#pragma unroll
        for (int r = 0; r < 4; ++r)
          if (kvb + r > qq) sacc[nf][r] = -1e30f;
      }
    }

    // P = exp(S) packed to f16 in-register; row-sum via dot2 on packed P
    uint pk[8];
#pragma unroll
    for (int nf = 0; nf < 4; ++nf) {
      float p0 = __expf(sacc[nf][0]);
      float p1 = __expf(sacc[nf][1]);
      float p2 = __expf(sacc[nf][2]);
      float p3 = __expf(sacc[nf][3]);
      pk[2 * nf]     = cvt_pk_f16(p0, p1);
      pk[2 * nf + 1] = cvt_pk_f16(p2, p3);
      psum0 = fdot2_ones(pk[2 * nf], psum0);
      psum1 = fdot2_ones(pk[2 * nf + 1], psum1);
    }

    // O += P V with permuted k-mapping; V fragments as 2x ds_read_b64
#pragma unroll
    for (int m = 0; m < 2; ++m) {
      union { uint u[4]; f16x8 v; } pu;
      pu.u[0] = pk[4 * m];     pu.u[1] = pk[4 * m + 1];
      pu.u[2] = pk[4 * m + 2]; pu.u[3] = pk[4 * m + 3];
      __builtin_amdgcn_s_setprio(1);
#pragma unroll
      for (int df = 0; df < 4; ++df) {
        union { f16x4 h[2]; f16x8 v; } vu;
        vu.h[0] = *(const f16x4*)(Vb + vlo[m][df]);
        vu.h[1] = *(const f16x4*)(Vb + vhi[m][df]);
        oacc[df] = __builtin_amdgcn_mfma_f32_16x16x32_f16(pu.v, vu.v, oacc[df], 0, 0, 0);
      }
      __builtin_amdgcn_s_setprio(0);
    }

    cur = (cur == 2) ? 0 : cur + 1;
  }

  float psum = psum0 + psum1;
  psum += __shfl_xor(psum, 16);
  psum += __shfl_xor(psum, 32);
  float pdiv[4];
#pragma unroll
  for (int r = 0; r < 4; ++r) pdiv[r] = __shfl(psum, g * 4 + r);

#pragma unroll
  for (int df = 0; df < 4; ++df)
#pragma unroll
    for (int r = 0; r < 4; ++r) {
      size_t rowg = (size_t)(b * SEQ + q0 + rg * 16 + g * 4 + r);
      AO[rowg * HID + h * 64 + df * 16 + lr] = (f16)(oacc[df][r] / pdiv[r]);
    }
}

// ---------------- launch ----------------
extern "C" void kernel_launch(void* const* d_in, const int* in_sizes, int n_in,
                              void* d_out, int out_size, void* d_ws, size_t ws_size,
                              hipStream_t stream) {
  const float* X  = (const float*)d_in[0];
  const float* Wq = (const float*)d_in[1];
  const float* Wk = (const float*)d_in[2];
  const float* Wv = (const float*)d_in[3];
  const float* Wo = (const float*)d_in[4];
  const float* qw = (const float*)d_in[5];
  const float* kw = (const float*)d_in[6];

  char* ws = (char*)d_ws;
  f16* Xb   = (f16*)(ws + 0);           // 4096 x 2048
  f16* Wqkv = (f16*)(ws + 16777216);    // 3072 x 2048 (Wq | Wk | Wv rows)
  f16* Wob  = (f16*)(ws + 29360128);    // 2048 x 2048
  f16* Qb   = (f16*)(ws + 37748736);    // 4096 x 2048
  f16* KVb  = (f16*)(ws + 54525952);    // 4096 x 1024 (K cols 0..511, V 512..1023)
  f16* VTb  = (f16*)(ws + 62914560);    // [2][8][64][2048]
  f16* AOb  = (f16*)(ws + 67108864);    // 4096 x 2048
  float* OUT = (float*)d_out;

  cvt_all<<<18432, 256, 0, stream>>>(X, Wq, Wk, Wv, Wo,
                                     Xb, Wqkv, Wqkv + 2048 * 2048, Wqkv + 2560 * 2048, Wob);

  // fused QKV projection: N=3072, split epilogue (Q stride 2048, KV stride 1024)
  gemm_bt<f16><<<dim3(24, 32), 256, 0, stream>>>(Xb, Wqkv, Qb, KVb,
                                                 4096, 3072, 2048, 2048, 2048, 1024);

  rmsnorm_all<<<40960, 256, 0, stream>>>(Qb, KVb, qw, kw);

  vtrans<<<dim3(32, 8, 2), 256, 0, stream>>>(KVb, VTb);
  attn<<<dim3(32, 32, 1), 512, 0, stream>>>(Qb, KVb, VTb, AOb);

  gemm_bt<float><<<dim3(16, 32), 256, 0, stream>>>(AOb, Wob, OUT, OUT,
                                                   4096, 2048, 2048, 2048, 2048, 2048);
}

// Round 8
// 169.268 us; speedup vs baseline: 2.4127x; 1.1356x over previous
//
#include <hip/hip_runtime.h>

typedef _Float16 f16;
typedef _Float16 f16x8 __attribute__((ext_vector_type(8)));
typedef _Float16 f16x4 __attribute__((ext_vector_type(4)));
typedef __fp16 fp16x2 __attribute__((ext_vector_type(2)));
typedef float f32x4 __attribute__((ext_vector_type(4)));

#define HID 2048
#define NH 32
#define NKV 8
#define HD 64
#define SEQ 2048
#define NB 2

__device__ __forceinline__ void gload_lds16(const void* g, void* l) {
  __builtin_amdgcn_global_load_lds((const __attribute__((address_space(1))) void*)g,
                                   (__attribute__((address_space(3))) void*)l, 16, 0, 0);
}

__device__ __forceinline__ uint cvt_pk_f16(float a, float b) {
  auto v = __builtin_amdgcn_cvt_pkrtz(a, b);   // __fp16 ext_vector(2)
  uint u;
  __builtin_memcpy(&u, &v, 4);
  return u;
}

__device__ __forceinline__ float fdot2_ones(uint pk, float acc) {
  fp16x2 a;
  __builtin_memcpy(&a, &pk, 4);
  fp16x2 ones = {(__fp16)1.0f, (__fp16)1.0f};
  return __builtin_amdgcn_fdot2(a, ones, acc, false);
}

// ---------------- fused f32 -> f16 convert of all 5 tensors ----------------
__global__ __launch_bounds__(256) void cvt_all(const float* __restrict__ X,
                                               const float* __restrict__ Wq,
                                               const float* __restrict__ Wk,
                                               const float* __restrict__ Wv,
                                               const float* __restrict__ Wo,
                                               f16* __restrict__ Xb, f16* __restrict__ Wqb,
                                               f16* __restrict__ Wkb, f16* __restrict__ Wvb,
                                               f16* __restrict__ Wob) {
  long i = (long)blockIdx.x * 256 + threadIdx.x;
  const float* s; f16* d; long o;
  if (i < 2097152)      { s = X;  d = Xb;  o = i; }
  else if (i < 3145728) { s = Wq; d = Wqb; o = i - 2097152; }
  else if (i < 3407872) { s = Wk; d = Wkb; o = i - 3145728; }
  else if (i < 3670016) { s = Wv; d = Wvb; o = i - 3407872; }
  else                  { s = Wo; d = Wob; o = i - 3670016; }
  float4 v = ((const float4*)s)[o];
  f16x4 ov = { (f16)v.x, (f16)v.y, (f16)v.z, (f16)v.w };
  ((f16x4*)d)[o] = ov;
}

// ---------------- GEMM: C[M,N] = A[M,K] * B[N,K]^T ----------------
// 128x128 tile, BK=64, 4 waves, counted-vmcnt 2-barrier pipeline (815 TF).
// T1 XCD swizzle, T2 slot swizzle, T5 setprio. Split epilogue.
template <typename CT>
__global__ __launch_bounds__(256) void gemm_bt(const f16* __restrict__ A,
                                               const f16* __restrict__ Bm,
                                               CT* __restrict__ C0, CT* __restrict__ C1,
                                               int M, int N, int K,
                                               int n_split, int ldc0, int ldc1) {
  __shared__ f16 As[2][128 * 64];
  __shared__ f16 Bs[2][128 * 64];
  const int t = threadIdx.x;
  const int lane = t & 63;
  const int w = t >> 6;
  const int wr = w >> 1, wc = w & 1;
  const int g = lane >> 4;
  const int lr = lane & 15;

  const int nwg = gridDim.x * gridDim.y;
  const int orig = blockIdx.y * gridDim.x + blockIdx.x;
  const int wg = (orig & 7) * (nwg >> 3) + (orig >> 3);
  const int m0 = (wg / gridDim.x) * 128;
  const int n0 = (wg % gridDim.x) * 128;

  f32x4 acc[4][4] = {};

  const int nkt = K / 64;

  auto stage = [&](int buf, int kt) {
    const int k0 = kt * 64;
#pragma unroll
    for (int i = 0; i < 4; ++i) {
      int c = w * 4 + i;
      int o = c * 1024 + lane * 16;
      int row = o >> 7;
      int ss = ((o >> 4) & 7) ^ (row & 7);
      const char* srcA = (const char*)A + ((size_t)(m0 + row) * K + k0) * 2 + ss * 16;
      gload_lds16(srcA, (char*)(&As[buf][0]) + c * 1024);
      const char* srcB = (const char*)Bm + ((size_t)(n0 + row) * K + k0) * 2 + ss * 16;
      gload_lds16(srcB, (char*)(&Bs[buf][0]) + c * 1024);
    }
  };

  stage(0, 0);
  if (nkt > 1) stage(1, 1);
  for (int kt = 0; kt < nkt; ++kt) {
    const int cur = kt & 1;
    if (kt + 1 < nkt) asm volatile("s_waitcnt vmcnt(8)" ::: "memory");
    else              asm volatile("s_waitcnt vmcnt(0)" ::: "memory");
    __builtin_amdgcn_s_barrier();
    __builtin_amdgcn_sched_barrier(0);

    f16x8 af[2][4], bf[2][4];
#pragma unroll
    for (int ks = 0; ks < 2; ++ks)
#pragma unroll
      for (int mf = 0; mf < 4; ++mf) {
        int row = wr * 64 + mf * 16 + lr;
        int slot = (g + 4 * ks) ^ (row & 7);
        af[ks][mf] = *(const f16x8*)((const char*)(&As[cur][0]) + row * 128 + slot * 16);
      }
#pragma unroll
    for (int ks = 0; ks < 2; ++ks)
#pragma unroll
      for (int nf = 0; nf < 4; ++nf) {
        int row = wc * 64 + nf * 16 + lr;
        int slot = (g + 4 * ks) ^ (row & 7);
        bf[ks][nf] = *(const f16x8*)((const char*)(&Bs[cur][0]) + row * 128 + slot * 16);
      }
    asm volatile("s_waitcnt lgkmcnt(0)" ::: "memory");
    __builtin_amdgcn_sched_barrier(0);
    __builtin_amdgcn_s_barrier();

    if (kt + 2 < nkt) stage(cur, kt + 2);

    __builtin_amdgcn_s_setprio(1);
#pragma unroll
    for (int ks = 0; ks < 2; ++ks)
#pragma unroll
      for (int mf = 0; mf < 4; ++mf)
#pragma unroll
        for (int nf = 0; nf < 4; ++nf)
          acc[mf][nf] = __builtin_amdgcn_mfma_f32_16x16x32_f16(af[ks][mf], bf[ks][nf], acc[mf][nf], 0, 0, 0);
    __builtin_amdgcn_s_setprio(0);
  }

  CT* Cp; int ldc, nb;
  if (n0 < n_split) { Cp = C0; ldc = ldc0; nb = n0; }
  else              { Cp = C1; ldc = ldc1; nb = n0 - n_split; }
#pragma unroll
  for (int mf = 0; mf < 4; ++mf)
#pragma unroll
    for (int nf = 0; nf < 4; ++nf)
#pragma unroll
      for (int r = 0; r < 4; ++r) {
        int mm = m0 + wr * 64 + mf * 16 + g * 4 + r;
        int nn = nb + wc * 64 + nf * 16 + lr;
        Cp[(size_t)mm * ldc + nn] = (CT)acc[mf][nf][r];
      }
}

// ---------------- V transpose + K RMSNorm ----------------
// K rows (head hk, 64 s-rows) RMS-normalized in place (8-lane shfl groups).
// V written transposed to VT[b][hk][d][s] with the PV k-permutation baked in:
// column pos holds original k(pos) = (pos&32) | h<<4 | a<<3 | b<<2 | c where
// pos = 32m'+8g+4h+c, g=2a+b  ->  attn PV B-fragment is a single conflict-free
// ds_read_b128 (same slot structure as the K-read, which measures 0 conflicts).
__global__ __launch_bounds__(256) void vtrans(f16* __restrict__ KV,
                                              f16* __restrict__ VT,
                                              const float* __restrict__ kw) {
  __shared__ f16 tile[64][72];
  int t = threadIdx.x;
  int st = blockIdx.x, hk = blockIdx.y, b = blockIdx.z;

  // --- K RMSNorm in place ---
#pragma unroll
  for (int p = 0; p < 2; ++p) {
    int idx = p * 256 + t;
    int s = idx >> 3, c8 = (idx & 7) * 8;
    f16* kp = KV + (size_t)(b * SEQ + st * 64 + s) * 1024 + hk * 64 + c8;
    f16x8 kv = *(const f16x8*)kp;
    float ss = 0.f;
#pragma unroll
    for (int j = 0; j < 8; ++j) { float x = (float)kv[j]; ss += x * x; }
    ss += __shfl_xor(ss, 1); ss += __shfl_xor(ss, 2); ss += __shfl_xor(ss, 4);
    float sc = rsqrtf(ss * (1.0f / 64.0f) + 1e-6f);
    f16x8 on;
#pragma unroll
    for (int j = 0; j < 8; ++j) on[j] = (f16)((float)kv[j] * sc * kw[c8 + j]);
    *(f16x8*)kp = on;
  }

  // --- V transpose with k-permutation ---
#pragma unroll
  for (int p = 0; p < 2; ++p) {
    int idx = p * 256 + t;
    int s = idx >> 3, c8 = (idx & 7) * 8;
    f16x8 v = *(const f16x8*)(KV + (size_t)(b * SEQ + st * 64 + s) * 1024 + 512 + hk * 64 + c8);
    *(f16x8*)(&tile[s][c8]) = v;
  }
  __syncthreads();
#pragma unroll
  for (int p = 0; p < 2; ++p) {
    int idx = p * 256 + t;
    int d = idx >> 3, s8 = (idx & 7) * 8;
    f16x8 ov;
#pragma unroll
    for (int j = 0; j < 8; ++j) {
      int pos = s8 + j;
      int k = (pos & 32) | (((pos >> 2) & 1) << 4) | (((pos >> 4) & 1) << 3)
            | (((pos >> 3) & 1) << 2) | (pos & 3);
      ov[j] = tile[k][d];
    }
    *(f16x8*)(VT + ((size_t)((b * NKV + hk) * 64) + d) * SEQ + st * 64 + s8) = ov;
  }
}

// ---------------- causal GQA flash attention (+ fused Q RMSNorm) ----------
// block = (col = hpair*2+b on x, qt-rank on y): 8 waves = 2 heads x 4 row-groups.
// Swapped QK^T keeps P in registers; PV reads single b128 (permuted VT layout).
// Fixed-max softmax; 3-buffer staging, counted vmcnt + raw barrier; global LPT.
__global__ __launch_bounds__(512) void attn(const f16* __restrict__ Q,
                                            const f16* __restrict__ KV,
                                            const f16* __restrict__ VT,
                                            f16* __restrict__ AO,
                                            const float* __restrict__ qw) {
  __shared__ f16 Ks[3][64 * 64];   // [kv][d], slot-swizzled
  __shared__ f16 Vs[3][64 * 64];   // permuted V^T: [d][kperm], slot-swizzled
  const int t = threadIdx.x, lane = t & 63, w = t >> 6;
  const int g = lane >> 4, lr = lane & 15;
  const int col = blockIdx.x;            // hpair*2 + b
  const int qt = 31 - blockIdx.y;        // heaviest first (true global LPT)
  const int b = col & 1;
  const int h = 2 * (col >> 1) + (w >> 2);
  const int rg = w & 3;
  const int hk = h >> 2;
  const int q0 = qt * 64;

  const size_t qrow = (size_t)(b * SEQ + q0 + rg * 16 + lr);
  f16x8 qf[2];
  qf[0] = *(const f16x8*)(Q + qrow * HID + h * 64 + g * 8);
  qf[1] = *(const f16x8*)(Q + qrow * HID + h * 64 + g * 8 + 32);

  // fused Q RMSNorm: lanes {lr, lr+16, lr+32, lr+48} hold the full 64-d row
  {
    float ss = 0.f;
#pragma unroll
    for (int i = 0; i < 2; ++i)
#pragma unroll
      for (int j = 0; j < 8; ++j) { float x = (float)qf[i][j]; ss += x * x; }
    ss += __shfl_xor(ss, 16); ss += __shfl_xor(ss, 32);
    float sc = rsqrtf(ss * (1.0f / 64.0f) + 1e-6f) * 0.125f;  // fold 1/sqrt(64)
    const float4* qw4 = (const float4*)qw;
    float4 w0 = qw4[2 * g], w1 = qw4[2 * g + 1];
    float4 w2 = qw4[2 * g + 8], w3 = qw4[2 * g + 9];
    qf[0][0] = (f16)((float)qf[0][0] * sc * w0.x);
    qf[0][1] = (f16)((float)qf[0][1] * sc * w0.y);
    qf[0][2] = (f16)((float)qf[0][2] * sc * w0.z);
    qf[0][3] = (f16)((float)qf[0][3] * sc * w0.w);
    qf[0][4] = (f16)((float)qf[0][4] * sc * w1.x);
    qf[0][5] = (f16)((float)qf[0][5] * sc * w1.y);
    qf[0][6] = (f16)((float)qf[0][6] * sc * w1.z);
    qf[0][7] = (f16)((float)qf[0][7] * sc * w1.w);
    qf[1][0] = (f16)((float)qf[1][0] * sc * w2.x);
    qf[1][1] = (f16)((float)qf[1][1] * sc * w2.y);
    qf[1][2] = (f16)((float)qf[1][2] * sc * w2.z);
    qf[1][3] = (f16)((float)qf[1][3] * sc * w2.w);
    qf[1][4] = (f16)((float)qf[1][4] * sc * w3.x);
    qf[1][5] = (f16)((float)qf[1][5] * sc * w3.y);
    qf[1][6] = (f16)((float)qf[1][6] * sc * w3.z);
    qf[1][7] = (f16)((float)qf[1][7] * sc * w3.w);
  }

  // hoisted LDS byte offsets (loop-invariant across kv tiles)
  int koff[2][4], voff[2][4];
#pragma unroll
  for (int ks = 0; ks < 2; ++ks)
#pragma unroll
    for (int nf = 0; nf < 4; ++nf) {
      int row = nf * 16 + lr;
      koff[ks][nf] = row * 128 + (((g + 4 * ks) ^ (row & 7)) * 16);
    }
#pragma unroll
  for (int m = 0; m < 2; ++m)
#pragma unroll
    for (int df = 0; df < 4; ++df) {
      int row = df * 16 + lr;
      voff[m][df] = row * 128 + (((4 * m + g) ^ (row & 7)) * 16);
    }

  f32x4 oacc[4] = {};
  float psum0 = 0.0f, psum1 = 0.0f;

  const int nkt = qt + 1;

  auto stage = [&](int buf, int kt2) {
    int o = w * 1024 + lane * 16;
    int row = o >> 7;
    int ss = ((o >> 4) & 7) ^ (row & 7);
    gload_lds16((const char*)KV + ((size_t)(b * SEQ + kt2 * 64 + row) * 1024 + hk * 64) * 2 + ss * 16,
                (char*)(&Ks[buf][0]) + w * 1024);
    gload_lds16((const char*)VT + (((size_t)((b * NKV + hk) * 64) + row) * SEQ + kt2 * 64) * 2 + ss * 16,
                (char*)(&Vs[buf][0]) + w * 1024);
  };

  stage(0, 0);
  if (nkt > 1) stage(1, 1);
  int cur = 0;
  for (int kt = 0; kt < nkt; ++kt) {
    // tile-kt loads guaranteed done; newer (kt+1) loads stay in flight
    if (kt + 1 < nkt) asm volatile("s_waitcnt vmcnt(2)" ::: "memory");
    else              asm volatile("s_waitcnt vmcnt(0)" ::: "memory");
    __builtin_amdgcn_s_barrier();
    asm volatile("" ::: "memory");

    if (kt + 2 < nkt) {
      int nb = cur + 2; if (nb >= 3) nb -= 3;
      stage(nb, kt + 2);
    }

    const char* Kb = (const char*)(&Ks[cur][0]);
    const char* Vb = (const char*)(&Vs[cur][0]);

    // S^T = K Q^T : lane holds S[q=lr][k = nf*16 + g*4 + r]
    f32x4 sacc[4] = {};
#pragma unroll
    for (int ks = 0; ks < 2; ++ks) {
      __builtin_amdgcn_s_setprio(1);
#pragma unroll
      for (int nf = 0; nf < 4; ++nf) {
        f16x8 kf = *(const f16x8*)(Kb + koff[ks][nf]);
        sacc[nf] = __builtin_amdgcn_mfma_f32_16x16x32_f16(kf, qf[ks], sacc[nf], 0, 0, 0);
      }
      __builtin_amdgcn_s_setprio(0);
    }

    if (kt == qt) {  // diagonal tile: causal mask (q = q0+rg*16+lr, lane-const)
      int qq = q0 + rg * 16 + lr;
#pragma unroll
      for (int nf = 0; nf < 4; ++nf) {
        int kvb = kt * 64 + nf * 16 + g * 4;
#pragma unroll
        for (int r = 0; r < 4; ++r)
          if (kvb + r > qq) sacc[nf][r] = -1e30f;
      }
    }

    // P = exp(S) packed to f16 in-register; row-sum via dot2 on packed P
    uint pk[8];
#pragma unroll
    for (int nf = 0; nf < 4; ++nf) {
      float p0 = __expf(sacc[nf][0]);
      float p1 = __expf(sacc[nf][1]);
      float p2 = __expf(sacc[nf][2]);
      float p3 = __expf(sacc[nf][3]);
      pk[2 * nf]     = cvt_pk_f16(p0, p1);
      pk[2 * nf + 1] = cvt_pk_f16(p2, p3);
      psum0 = fdot2_ones(pk[2 * nf], psum0);
      psum1 = fdot2_ones(pk[2 * nf + 1], psum1);
    }

    // O += P V; V fragment = single b128 (layout permutation matches P's k-map)
#pragma unroll
    for (int m = 0; m < 2; ++m) {
      union { uint u[4]; f16x8 v; } pu;
      pu.u[0] = pk[4 * m];     pu.u[1] = pk[4 * m + 1];
      pu.u[2] = pk[4 * m + 2]; pu.u[3] = pk[4 * m + 3];
      __builtin_amdgcn_s_setprio(1);
#pragma unroll
      for (int df = 0; df < 4; ++df) {
        f16x8 vf = *(const f16x8*)(Vb + voff[m][df]);
        oacc[df] = __builtin_amdgcn_mfma_f32_16x16x32_f16(pu.v, vf, oacc[df], 0, 0, 0);
      }
      __builtin_amdgcn_s_setprio(0);
    }

    cur = (cur == 2) ? 0 : cur + 1;
  }

  float psum = psum0 + psum1;
  psum += __shfl_xor(psum, 16);
  psum += __shfl_xor(psum, 32);
  float pdiv[4];
#pragma unroll
  for (int r = 0; r < 4; ++r) pdiv[r] = __shfl(psum, g * 4 + r);

#pragma unroll
  for (int df = 0; df < 4; ++df)
#pragma unroll
    for (int r = 0; r < 4; ++r) {
      size_t rowg = (size_t)(b * SEQ + q0 + rg * 16 + g * 4 + r);
      AO[rowg * HID + h * 64 + df * 16 + lr] = (f16)(oacc[df][r] / pdiv[r]);
    }
}

// ---------------- launch ----------------
extern "C" void kernel_launch(void* const* d_in, const int* in_sizes, int n_in,
                              void* d_out, int out_size, void* d_ws, size_t ws_size,
                              hipStream_t stream) {
  const float* X  = (const float*)d_in[0];
  const float* Wq = (const float*)d_in[1];
  const float* Wk = (const float*)d_in[2];
  const float* Wv = (const float*)d_in[3];
  const float* Wo = (const float*)d_in[4];
  const float* qw = (const float*)d_in[5];
  const float* kw = (const float*)d_in[6];

  char* ws = (char*)d_ws;
  f16* Xb   = (f16*)(ws + 0);           // 4096 x 2048
  f16* Wqkv = (f16*)(ws + 16777216);    // 3072 x 2048 (Wq | Wk | Wv rows)
  f16* Wob  = (f16*)(ws + 29360128);    // 2048 x 2048
  f16* Qb   = (f16*)(ws + 37748736);    // 4096 x 2048
  f16* KVb  = (f16*)(ws + 54525952);    // 4096 x 1024 (K cols 0..511, V 512..1023)
  f16* VTb  = (f16*)(ws + 62914560);    // [2][8][64][2048] permuted V^T
  f16* AOb  = (f16*)(ws + 67108864);    // 4096 x 2048
  float* OUT = (float*)d_out;

  cvt_all<<<18432, 256, 0, stream>>>(X, Wq, Wk, Wv, Wo,
                                     Xb, Wqkv, Wqkv + 2048 * 2048, Wqkv + 2560 * 2048, Wob);

  // fused QKV projection: N=3072, split epilogue (Q stride 2048, KV stride 1024)
  gemm_bt<f16><<<dim3(24, 32), 256, 0, stream>>>(Xb, Wqkv, Qb, KVb,
                                                 4096, 3072, 2048, 2048, 2048, 1024);

  vtrans<<<dim3(32, 8, 2), 256, 0, stream>>>(KVb, VTb, kw);
  attn<<<dim3(32, 32, 1), 512, 0, stream>>>(Qb, KVb, VTb, AOb, qw);

  gemm_bt<float><<<dim3(16, 32), 256, 0, stream>>>(AOb, Wob, OUT, OUT,
                                                   4096, 2048, 2048, 2048, 2048, 2048);
}